// Round 4
// baseline (1170.902 us; speedup 1.0000x reference)
//
#include <hip/hip_runtime.h>
#include <math.h>

namespace {

constexpr int T = 5, N = 2048, K = 20, E = 512;
constexpr int H = 64, U = 8;
constexpr int CAP = 512;           // max neighbors kept (measured mean ~103)
constexpr float SLOPE = 0.01f;

typedef __attribute__((ext_vector_type(8))) short short8;
typedef __attribute__((ext_vector_type(4))) float f32x4;

__device__ inline float sigm(float x) { return 1.0f / (1.0f + expf(-x)); }

// split fp32 -> bf16 hi + bf16 lo (truncation; x ~= hi+lo with rel err <= 2^-16)
__device__ inline void bsplit(float x, short& hi, short& lo) {
  unsigned u = __float_as_uint(x);
  hi = (short)(u >> 16);
  float r = x - __uint_as_float(u & 0xFFFF0000u);
  lo = (short)(__float_as_uint(r) >> 16);
}

__device__ inline float rdlane(float v, int lane) {
  return __int_as_float(__builtin_amdgcn_readlane(__float_as_int(v), lane));
}

// ---------------- prep: Wih_m -> MFMA B-fragment blocks, Whh_m -> transposed ----
// Bf layout: frag f = ((bk*2+kc)*12 + nt)*2 + hl, each 512 shorts (1KB).
// inner offset = koct*128 + c16*8 + j  (lane l reads l*8..l*8+7 => koct=l>>4, c16=l&15)
// element (o,k): o = nt*16+c16 (Wih row), k = bk*64 + kc*32 + koct*8 + j
__global__ __launch_bounds__(256) void k_prep(
    const float* __restrict__ Wih, const float* __restrict__ Whh,
    short* __restrict__ Bf, float* __restrict__ WhhT)
{
  for (int idx = threadIdx.x + blockIdx.x * 256; idx < 192 * E; idx += 256 * 64) {
    const int o = idx >> 9, k = idx & 511;
    short hi, lo; bsplit(Wih[idx], hi, lo);
    const int bk = k >> 6, kc = (k >> 5) & 1, koct = (k >> 3) & 3, j = k & 7;
    const int nt = o >> 4, c16 = o & 15;
    const long f = ((long)(bk * 2 + kc) * 12 + nt) * 2;
    const int off = koct * 128 + c16 * 8 + j;
    Bf[f * 512 + off] = hi;
    Bf[(f + 1) * 512 + off] = lo;
  }
  for (int idx = threadIdx.x + blockIdx.x * 256; idx < 64 * 192; idx += 256 * 64) {
    const int k2 = idx / 192, row = idx % 192;
    WhhT[idx] = Whh[row * 64 + k2];
  }
}

// ---------------- gi GEMM: [rows,512] x [512,192], bf16 MFMA split-precision ------
// 256 thr / 4 waves; wave M=48 (mf=3), N=192 (nt=12), BK=64.
// A: direct global->reg fragments (16 rows x 128B lines, fully used).
// B: fragment blocks staged LDS via global_load_lds (linear both sides, 0 conflicts).
__global__ __launch_bounds__(256) void k_gemm(
    const float* __restrict__ m, const short* __restrict__ Bf,
    const float* __restrict__ bih, float* __restrict__ gi,
    const long row0, const long rowsTot)
{
  __shared__ alignas(16) short Bc[48 * 512];   // 48 KB
  const int tid = threadIdx.x, w = tid >> 6, l = tid & 63;
  const int lr = l & 15, g = l >> 4;
  const long blkrow = (long)blockIdx.x * 192;

  f32x4 acc[3][12];
  #pragma unroll
  for (int mf = 0; mf < 3; ++mf)
    #pragma unroll
    for (int nt = 0; nt < 12; ++nt) acc[mf][nt] = (f32x4){0.f, 0.f, 0.f, 0.f};

  for (int bk = 0; bk < 8; ++bk) {
    // ---- B: async global->LDS, 48 x 1KB linear chunks ----
    const short* __restrict__ bsrc = Bf + (long)bk * (48 * 512);
    #pragma unroll
    for (int i = 0; i < 12; ++i) {
      const int c = w + i * 4;
      __builtin_amdgcn_global_load_lds(
          (const __attribute__((address_space(1))) void*)(bsrc + c * 512 + l * 8),
          (__attribute__((address_space(3))) void*)(&Bc[c * 512]), 16, 0, 0);
    }
    // ---- A: fragments straight into registers ----
    short8 ah[2][3], al[2][3];
    #pragma unroll
    for (int kc = 0; kc < 2; ++kc)
      #pragma unroll
      for (int mf = 0; mf < 3; ++mf) {
        long r = blkrow + w * 48 + mf * 16 + lr;
        if (r >= rowsTot) r = rowsTot - 1;
        const float* __restrict__ src = m + (row0 + r) * E + bk * 64 + kc * 32 + g * 8;
        const float4 v0 = *reinterpret_cast<const float4*>(src);
        const float4 v1 = *reinterpret_cast<const float4*>(src + 4);
        short h0,l0,h1,l1,h2,l2,h3,l3,h4,l4,h5,l5,h6,l6,h7,l7;
        bsplit(v0.x,h0,l0); bsplit(v0.y,h1,l1); bsplit(v0.z,h2,l2); bsplit(v0.w,h3,l3);
        bsplit(v1.x,h4,l4); bsplit(v1.y,h5,l5); bsplit(v1.z,h6,l6); bsplit(v1.w,h7,l7);
        ah[kc][mf] = (short8){h0,h1,h2,h3,h4,h5,h6,h7};
        al[kc][mf] = (short8){l0,l1,l2,l3,l4,l5,l6,l7};
      }
    __syncthreads();   // B staged (drains vmcnt+lgkmcnt)

    #pragma unroll
    for (int kc = 0; kc < 2; ++kc) {
      #pragma unroll
      for (int nt = 0; nt < 12; ++nt) {
        const short8 bh = *reinterpret_cast<const short8*>(&Bc[((kc * 12 + nt) * 2 + 0) * 512 + l * 8]);
        const short8 bl = *reinterpret_cast<const short8*>(&Bc[((kc * 12 + nt) * 2 + 1) * 512 + l * 8]);
        #pragma unroll
        for (int mf = 0; mf < 3; ++mf) {
          acc[mf][nt] = __builtin_amdgcn_mfma_f32_16x16x32_bf16(ah[kc][mf], bh, acc[mf][nt], 0, 0, 0);
          acc[mf][nt] = __builtin_amdgcn_mfma_f32_16x16x32_bf16(al[kc][mf], bh, acc[mf][nt], 0, 0, 0);
          acc[mf][nt] = __builtin_amdgcn_mfma_f32_16x16x32_bf16(ah[kc][mf], bl, acc[mf][nt], 0, 0, 0);
        }
      }
    }
    __syncthreads();   // protect Bc before next stage
  }

  // epilogue: C/D layout col = lane&15, row = (lane>>4)*4 + reg
  #pragma unroll
  for (int mf = 0; mf < 3; ++mf) {
    const long rbase = blkrow + w * 48 + mf * 16 + g * 4;
    #pragma unroll
    for (int nt = 0; nt < 12; ++nt) {
      const int col = nt * 16 + lr;
      const float bb = bih[col];
      #pragma unroll
      for (int i = 0; i < 4; ++i) {
        const long r = rbase + i;
        if (r < rowsTot) gi[r * 192 + col] = acc[mf][nt][i] + bb;
      }
    }
  }
}

// ---------------- recurrence over K=20 using precomputed gi ----------------
// wave owns 4 seqs, lane = hidden unit; h in regs, broadcast via readlane.
__global__ __launch_bounds__(256) void k_recur(
    const float* __restrict__ gi, const float* __restrict__ WhhT,
    const float* __restrict__ bhh, float* __restrict__ rout, const int seq0)
{
  __shared__ float wsh[64][192];   // 48 KB, [k2][gate*64+unit]
  const int tid = threadIdx.x;
  for (int idx = tid; idx < 64 * 192; idx += 256) wsh[idx / 192][idx % 192] = WhhT[idx];
  __syncthreads();

  const int w = tid >> 6, l = tid & 63;
  const int lseq0 = blockIdx.x * 16 + w * 4;
  const float bR = bhh[l], bZ = bhh[64 + l], bN = bhh[128 + l];
  float h[4] = {0.f, 0.f, 0.f, 0.f};
  float rsum[4] = {0.f, 0.f, 0.f, 0.f};

  for (int k = 0; k < K; ++k) {
    float aR[4], aZ[4], aN[4], gR[4], gZ[4], gN[4];
    #pragma unroll
    for (int ii = 0; ii < 4; ++ii) {
      const long row = ((long)(lseq0 + ii) * K + k) * 192;
      gR[ii] = gi[row + l]; gZ[ii] = gi[row + 64 + l]; gN[ii] = gi[row + 128 + l];
      aR[ii] = bR; aZ[ii] = bZ; aN[ii] = bN;
    }
    #pragma unroll 16
    for (int k2 = 0; k2 < H; ++k2) {
      const float wr = wsh[k2][l], wz = wsh[k2][64 + l], wn = wsh[k2][128 + l];
      #pragma unroll
      for (int ii = 0; ii < 4; ++ii) {
        const float hk = rdlane(h[ii], k2);
        aR[ii] += wr * hk; aZ[ii] += wz * hk; aN[ii] += wn * hk;
      }
    }
    #pragma unroll
    for (int ii = 0; ii < 4; ++ii) {
      const float r = sigm(gR[ii] + aR[ii]);
      const float z = sigm(gZ[ii] + aZ[ii]);
      const float nn = tanhf(gN[ii] + r * aN[ii]);
      h[ii] = (1.f - z) * nn + z * h[ii];
      rsum[ii] += h[ii];
    }
  }
  #pragma unroll
  for (int ii = 0; ii < 4; ++ii) {
    const int gseq = seq0 + lseq0 + ii;
    const int tt = gseq / N, n = gseq % N;
    rout[(n * T + tt) * H + l] = rsum[ii];
  }
}

// ---------------- GRU over p, q = sum_t h ----------------
__global__ __launch_bounds__(256) void k_gru_p(
    const float* __restrict__ p, const float* __restrict__ Wih,
    const float* __restrict__ Whh, const float* __restrict__ bih,
    const float* __restrict__ bhh, float* __restrict__ q)
{
  __shared__ float hs[4][H];
  const int w = threadIdx.x >> 6, lane = threadIdx.x & 63;
  const int n = blockIdx.x * 4 + w;
  hs[w][lane] = 0.f;
  float h = 0.f, qs = 0.f;
  __syncthreads();
  for (int t = 0; t < T; ++t) {
    const float x0 = p[n * (T * 3) + t * 3 + 0];
    const float x1 = p[n * (T * 3) + t * 3 + 1];
    const float x2 = p[n * (T * 3) + t * 3 + 2];
    float gr = bih[lane]     + Wih[lane * 3] * x0       + Wih[lane * 3 + 1] * x1       + Wih[lane * 3 + 2] * x2;
    float gz = bih[64 + lane]  + Wih[(64 + lane) * 3] * x0  + Wih[(64 + lane) * 3 + 1] * x1  + Wih[(64 + lane) * 3 + 2] * x2;
    float gn = bih[128 + lane] + Wih[(128 + lane) * 3] * x0 + Wih[(128 + lane) * 3 + 1] * x1 + Wih[(128 + lane) * 3 + 2] * x2;
    float hr = bhh[lane], hz = bhh[64 + lane], hn = bhh[128 + lane];
    #pragma unroll 8
    for (int k2 = 0; k2 < H; ++k2) {
      const float hk = hs[w][k2];
      hr += Whh[lane * H + k2] * hk;
      hz += Whh[(64 + lane) * H + k2] * hk;
      hn += Whh[(128 + lane) * H + k2] * hk;
    }
    const float r = sigm(gr + hr), z = sigm(gz + hz);
    const float nn = tanhf(gn + r * hn);
    h = (1.f - z) * nn + z * h;
    qs += h;
    __syncthreads();
    hs[w][lane] = h;
    __syncthreads();
  }
  q[n * H + lane] = qs;
}

// ---------------- GRU over r, c = sum_t h ----------------
__global__ __launch_bounds__(256) void k_gru_s(
    const float* __restrict__ rin, const float* __restrict__ Wih,
    const float* __restrict__ Whh, const float* __restrict__ bih,
    const float* __restrict__ bhh, float* __restrict__ c)
{
  __shared__ float hs[4][H];
  __shared__ float xsh[4][H];
  const int w = threadIdx.x >> 6, lane = threadIdx.x & 63;
  const int n = blockIdx.x * 4 + w;
  hs[w][lane] = 0.f;
  float h = 0.f, cs = 0.f;
  __syncthreads();
  for (int t = 0; t < T; ++t) {
    xsh[w][lane] = rin[(n * T + t) * H + lane];
    __syncthreads();
    float gr = bih[lane], gz = bih[64 + lane], gn = bih[128 + lane];
    float hr = bhh[lane], hz = bhh[64 + lane], hn = bhh[128 + lane];
    #pragma unroll 8
    for (int k2 = 0; k2 < H; ++k2) {
      const float xk = xsh[w][k2];
      const float hk = hs[w][k2];
      gr += Wih[lane * H + k2] * xk;  gz += Wih[(64 + lane) * H + k2] * xk;  gn += Wih[(128 + lane) * H + k2] * xk;
      hr += Whh[lane * H + k2] * hk;  hz += Whh[(64 + lane) * H + k2] * hk;  hn += Whh[(128 + lane) * H + k2] * hk;
    }
    const float r = sigm(gr + hr), z = sigm(gz + hz);
    const float nn = tanhf(gn + r * hn);
    h = (1.f - z) * nn + z * h;
    cs += h;
    __syncthreads();
    hs[w][lane] = h;
    __syncthreads();
  }
  c[n * H + lane] = cs;
}

// ---------------- bilinear blend + relu ----------------
__global__ __launch_bounds__(256) void k_blend(
    const float* __restrict__ q, const float* __restrict__ c,
    const float* __restrict__ W, const float* __restrict__ b,
    float* __restrict__ xout)
{
  __shared__ alignas(16) float qs[4][H];
  __shared__ alignas(16) float cs[4][H];
  const int nl = threadIdx.x >> 6, o = threadIdx.x & 63;
  const int n = blockIdx.x * 4 + nl;
  qs[nl][o] = q[n * H + o];
  cs[nl][o] = c[n * H + o];
  __syncthreads();
  float acc = b[o];
  const float4* __restrict__ W4 = reinterpret_cast<const float4*>(W) + o * (H * H / 4);
  const float4* c4 = reinterpret_cast<const float4*>(&cs[nl][0]);
  for (int i = 0; i < H; ++i) {
    float part = 0.f;
    #pragma unroll 4
    for (int j4 = 0; j4 < H / 4; ++j4) {
      const float4 wv = W4[i * (H / 4) + j4];
      const float4 cv = c4[j4];
      part += wv.x * cv.x + wv.y * cv.y + wv.z * cv.z + wv.w * cv.w;
    }
    acc += qs[nl][i] * part;
  }
  xout[n * H + o] = fmaxf(acc, 0.f);
}

// ---------------- adjacency compaction ----------------
__global__ __launch_bounds__(256) void k_compact(
    const float* __restrict__ adj, int* __restrict__ nbr, int* __restrict__ deg)
{
  const int w = threadIdx.x >> 6, lane = threadIdx.x & 63;
  const int i = blockIdx.x * 4 + w;
  int base = 0;
  for (int j0 = 0; j0 < N; j0 += 64) {
    const float v = adj[(long)i * N + j0 + lane];
    const unsigned long long mask = __ballot(v > 0.f);
    const int pre = __popcll(mask & ((1ull << lane) - 1ull));
    if (v > 0.f && base + pre < CAP) nbr[i * CAP + base + pre] = j0 + lane;
    base += __popcll(mask);
  }
  if (lane == 0) deg[i] = base < CAP ? base : CAP;
}

// ---------------- GAT precompute: Wh [n][512], s1T/s2T [n][8] ----------------
__global__ __launch_bounds__(256) void k_gat_pre(
    const float* __restrict__ x, const float* __restrict__ W,
    const float* __restrict__ a, const int F,
    float* __restrict__ Wh, float* __restrict__ s1T, float* __restrict__ s2T)
{
  const int nl = threadIdx.x >> 6, o = threadIdx.x & 63;
  const int n = blockIdx.x * 4 + nl;
  const int u = blockIdx.y;
  const float* __restrict__ Wu = W + (long)u * F * 64;
  const float* __restrict__ xn = x + (long)n * F;
  float acc = 0.f;
  #pragma unroll 8
  for (int f = 0; f < F; ++f) acc += xn[f] * Wu[f * 64 + o];
  Wh[(long)n * 512 + u * 64 + o] = acc;
  float p1 = acc * a[u * 128 + o];
  float p2 = acc * a[u * 128 + 64 + o];
  #pragma unroll
  for (int d = 32; d > 0; d >>= 1) { p1 += __shfl_xor(p1, d, 64); p2 += __shfl_xor(p2, d, 64); }
  if (o == 0) { s1T[n * 8 + u] = p1; s2T[n * 8 + u] = p2; }
}

// ---------------- GAT attention: one node per wave, all 8 heads, online softmax --
__global__ __launch_bounds__(256) void k_attn(
    const float* __restrict__ Wh, const float* __restrict__ s1T,
    const float* __restrict__ s2T, const int* __restrict__ nbr,
    const int* __restrict__ deg, const int mode, float* __restrict__ out)
{
  const int w = threadIdx.x >> 6, l = threadIdx.x & 63;
  const int i = blockIdx.x * 4 + w;
  const int d = deg[i];
  float s1v[8];
  {
    const float4 a0 = *reinterpret_cast<const float4*>(&s1T[i * 8]);
    const float4 a1 = *reinterpret_cast<const float4*>(&s1T[i * 8 + 4]);
    s1v[0]=a0.x; s1v[1]=a0.y; s1v[2]=a0.z; s1v[3]=a0.w;
    s1v[4]=a1.x; s1v[5]=a1.y; s1v[6]=a1.z; s1v[7]=a1.w;
  }
  float mrun[8], lrun[8], acc[8];
  #pragma unroll
  for (int u = 0; u < 8; ++u) { mrun[u] = -1e30f; lrun[u] = 0.f; acc[u] = 0.f; }

  for (int t = 0; t < d; ++t) {
    const int j = nbr[i * CAP + t];
    const float4 b0 = *reinterpret_cast<const float4*>(&s2T[j * 8]);
    const float4 b1 = *reinterpret_cast<const float4*>(&s2T[j * 8 + 4]);
    const float s2v[8] = {b0.x, b0.y, b0.z, b0.w, b1.x, b1.y, b1.z, b1.w};
    const float* __restrict__ whrow = Wh + (long)j * 512 + l;
    #pragma unroll
    for (int u = 0; u < 8; ++u) {
      float e = s1v[u] + s2v[u];
      e = e > 0.f ? e : SLOPE * e;
      const float dlt = e - mrun[u];
      const float ex = __expf(-fabsf(dlt));     // exp(-|e - m|)
      const float pp = dlt <= 0.f ? ex : 1.f;   // exp(e - mnew)
      const float ff = dlt <= 0.f ? 1.f : ex;   // exp(mold - mnew)
      mrun[u] = dlt <= 0.f ? mrun[u] : e;
      const float whv = whrow[u * 64];
      acc[u] = acc[u] * ff + pp * whv;
      lrun[u] = lrun[u] * ff + pp;
    }
  }
  #pragma unroll
  for (int u = 0; u < 8; ++u) {
    const float v = acc[u] / lrun[u];
    float val;
    if (mode == 0) val = v > 0.f ? v : (expf(v) - 1.f);   // elu, alpha=1
    else           val = 1.f / (1.f + expf(-v));          // sigmoid
    out[(long)i * 512 + u * 64 + l] = val;
  }
}

// ---------------- final projection + sigmoid ----------------
__global__ __launch_bounds__(256) void k_final(
    const float* __restrict__ nz, const float* __restrict__ fw,
    const float* __restrict__ fb, float* __restrict__ out)
{
  const int w = threadIdx.x >> 6, lane = threadIdx.x & 63;
  const int n = blockIdx.x * 4 + w;
  float p = 0.f;
  #pragma unroll
  for (int f = lane; f < 512; f += 64) p += nz[(long)n * 512 + f] * fw[f];
  #pragma unroll
  for (int d = 32; d > 0; d >>= 1) p += __shfl_xor(p, d, 64);
  if (lane == 0) out[n] = 1.f / (1.f + expf(-(p + fb[0])));
}

}  // namespace

extern "C" void kernel_launch(void* const* d_in, const int* in_sizes, int n_in,
                              void* d_out, int out_size, void* d_ws, size_t ws_size,
                              hipStream_t stream)
{
  const float* p     = (const float*)d_in[0];
  const float* m     = (const float*)d_in[1];
  const float* adj   = (const float*)d_in[2];
  const float* Wih_p = (const float*)d_in[3];
  const float* Whh_p = (const float*)d_in[4];
  const float* bih_p = (const float*)d_in[5];
  const float* bhh_p = (const float*)d_in[6];
  const float* Wih_m = (const float*)d_in[7];
  const float* Whh_m = (const float*)d_in[8];
  const float* bih_m = (const float*)d_in[9];
  const float* bhh_m = (const float*)d_in[10];
  const float* Wih_s = (const float*)d_in[11];
  const float* Whh_s = (const float*)d_in[12];
  const float* bih_s = (const float*)d_in[13];
  const float* bhh_s = (const float*)d_in[14];
  // d_in[15..23]: lin-attn weights — unused (softmax over size-1 axis == 1)
  const float* blend_W = (const float*)d_in[24];
  const float* blend_b = (const float*)d_in[25];
  const float* g1W = (const float*)d_in[26];
  const float* g1a = (const float*)d_in[27];
  const float* g2W = (const float*)d_in[28];
  const float* g2a = (const float*)d_in[29];
  const float* finW = (const float*)d_in[30];
  const float* finb = (const float*)d_in[31];

  float* ws = (float*)d_ws;
  float* q    = ws;                  // N*H
  float* rr   = q + N * H;           // N*T*H
  float* c    = rr + N * T * H;      // N*H
  float* xb   = c + N * H;           // N*H
  float* Wh1  = xb + N * H;          // N*512  ([n][u*64+o])
  float* z    = Wh1 + (long)N * 512; // N*512
  float* Wh2  = z + (long)N * 512;   // N*512
  float* nz   = Wh2 + (long)N * 512; // N*512
  float* s1a  = nz + (long)N * 512;  // N*8 (transposed [n][u])
  float* s2a  = s1a + N * 8;         // N*8
  float* s1b  = s2a + N * 8;         // N*8
  float* s2b  = s1b + N * 8;         // N*8
  int*   nbr  = (int*)(s2b + N * 8); // N*CAP ints
  int*   deg  = nbr + (long)N * CAP; // N ints
  short* Bf   = (short*)(deg + N);   // 8*2*12*2*512 shorts (384 KB)
  float* WhhT = (float*)(Bf + 8 * 2 * 12 * 2 * 512);   // 64*192 fp32
  float* gi   = WhhT + 64 * 192;     // chunked

  // chunk the gi buffer to whatever scratch remains (deterministic in ws_size)
  const long avail = (long)(ws_size / 4) - (gi - ws);
  const long total_seqs = (long)T * N;                       // 10240
  long chunk = (avail / ((long)K * 192) / 32) * 32;          // multiple of 32 seqs
  if (chunk > total_seqs) chunk = total_seqs;
  if (chunk < 32) chunk = 32;

  k_prep<<<64, 256, 0, stream>>>(Wih_m, Whh_m, Bf, WhhT);
  k_gru_p<<<N / 4, 256, 0, stream>>>(p, Wih_p, Whh_p, bih_p, bhh_p, q);
  for (long s0 = 0; s0 < total_seqs; s0 += chunk) {
    const long cs = (total_seqs - s0) < chunk ? (total_seqs - s0) : chunk;
    const long rows = cs * K;
    k_gemm<<<(int)((rows + 191) / 192), 256, 0, stream>>>(m, Bf, bih_m, gi, s0 * K, rows);
    k_recur<<<(int)(cs / 16), 256, 0, stream>>>(gi, WhhT, bhh_m, rr, (int)s0);
  }
  k_gru_s<<<N / 4, 256, 0, stream>>>(rr, Wih_s, Whh_s, bih_s, bhh_s, c);
  k_blend<<<N / 4, 256, 0, stream>>>(q, c, blend_W, blend_b, xb);
  k_compact<<<N / 4, 256, 0, stream>>>(adj, nbr, deg);
  k_gat_pre<<<dim3(N / 4, U), 256, 0, stream>>>(xb, g1W, g1a, 64, Wh1, s1a, s2a);
  k_attn<<<N / 4, 256, 0, stream>>>(Wh1, s1a, s2a, nbr, deg, 0, z);
  k_gat_pre<<<dim3(N / 4, U), 256, 0, stream>>>(z, g2W, g2a, 512, Wh2, s1b, s2b);
  k_attn<<<N / 4, 256, 0, stream>>>(Wh2, s1b, s2b, nbr, deg, 1, nz);
  k_final<<<N / 4, 256, 0, stream>>>(nz, finW, finb, (float*)d_out);
}

// Round 5
// 1017.476 us; speedup vs baseline: 1.1508x; 1.1508x over previous
//
#include <hip/hip_runtime.h>
#include <math.h>

namespace {

constexpr int T = 5, N = 2048, K = 20, E = 512;
constexpr int H = 64, U = 8;
constexpr int CAP = 512;           // max neighbors kept (measured mean ~103)
constexpr float SLOPE = 0.01f;

typedef __attribute__((ext_vector_type(8))) short short8;
typedef __attribute__((ext_vector_type(4))) float f32x4;

__device__ inline float sigm(float x) { return 1.0f / (1.0f + expf(-x)); }

// split fp32 -> bf16 hi + bf16 lo (truncation; x ~= hi+lo with rel err <= 2^-16)
__device__ inline void bsplit(float x, short& hi, short& lo) {
  unsigned u = __float_as_uint(x);
  hi = (short)(u >> 16);
  float r = x - __uint_as_float(u & 0xFFFF0000u);
  lo = (short)(__float_as_uint(r) >> 16);
}

__device__ inline float rdlane(float v, int lane) {
  return __int_as_float(__builtin_amdgcn_readlane(__float_as_int(v), lane));
}

// ---------------- prep: Wih_m -> MFMA B-fragment blocks, Whh_m -> transposed ----
// Bf layout: frag f = ((bk*2+kc)*12 + nt)*2 + hl, each 512 shorts (1KB).
// inner offset = koct*128 + c16*8 + j  (lane l reads l*8..l*8+7 => koct=l>>4, c16=l&15)
// element (o,k): o = nt*16+c16 (Wih row), k = bk*64 + kc*32 + koct*8 + j
__global__ __launch_bounds__(256) void k_prep(
    const float* __restrict__ Wih, const float* __restrict__ Whh,
    short* __restrict__ Bf, float* __restrict__ WhhT)
{
  for (int idx = threadIdx.x + blockIdx.x * 256; idx < 192 * E; idx += 256 * 64) {
    const int o = idx >> 9, k = idx & 511;
    short hi, lo; bsplit(Wih[idx], hi, lo);
    const int bk = k >> 6, kc = (k >> 5) & 1, koct = (k >> 3) & 3, j = k & 7;
    const int nt = o >> 4, c16 = o & 15;
    const long f = ((long)(bk * 2 + kc) * 12 + nt) * 2;
    const int off = koct * 128 + c16 * 8 + j;
    Bf[f * 512 + off] = hi;
    Bf[(f + 1) * 512 + off] = lo;
  }
  for (int idx = threadIdx.x + blockIdx.x * 256; idx < 64 * 192; idx += 256 * 64) {
    const int k2 = idx / 192, row = idx % 192;
    WhhT[idx] = Whh[row * 64 + k2];
  }
}

// ---------------- gi GEMM: [rows,512] x [512,192], bf16 MFMA split-precision ------
// NO LDS, NO barriers. 256 thr / 4 waves; wave M=32 (mf=2), N=192.
// A: global->reg fragments; B: fragment blocks read straight from L2 (coalesced 1KB).
// __launch_bounds__(256,2): cap regs at 256 -> 2 waves/SIMD residency.
__global__ __launch_bounds__(256, 2) void k_gemm(
    const float* __restrict__ m, const short* __restrict__ Bf,
    const float* __restrict__ bih, float* __restrict__ gi, const long row0)
{
  const int tid = threadIdx.x, w = tid >> 6, l = tid & 63;
  const int lr = l & 15, g = l >> 4;
  const long blkrow = (long)blockIdx.x * 128;

  f32x4 acc[2][12];
  #pragma unroll
  for (int mf = 0; mf < 2; ++mf)
    #pragma unroll
    for (int nt = 0; nt < 12; ++nt) acc[mf][nt] = (f32x4){0.f, 0.f, 0.f, 0.f};

  for (int bk = 0; bk < 8; ++bk) {
    // ---- A fragments straight into registers ----
    short8 ah[2][2], al[2][2];
    #pragma unroll
    for (int kc = 0; kc < 2; ++kc)
      #pragma unroll
      for (int mf = 0; mf < 2; ++mf) {
        const long r = blkrow + w * 32 + mf * 16 + lr;
        const float* __restrict__ src = m + (row0 + r) * E + bk * 64 + kc * 32 + g * 8;
        const float4 v0 = *reinterpret_cast<const float4*>(src);
        const float4 v1 = *reinterpret_cast<const float4*>(src + 4);
        short h0,l0,h1,l1,h2,l2,h3,l3,h4,l4,h5,l5,h6,l6,h7,l7;
        bsplit(v0.x,h0,l0); bsplit(v0.y,h1,l1); bsplit(v0.z,h2,l2); bsplit(v0.w,h3,l3);
        bsplit(v1.x,h4,l4); bsplit(v1.y,h5,l5); bsplit(v1.z,h6,l6); bsplit(v1.w,h7,l7);
        ah[kc][mf] = (short8){h0,h1,h2,h3,h4,h5,h6,h7};
        al[kc][mf] = (short8){l0,l1,l2,l3,l4,l5,l6,l7};
      }
    // ---- B fragments from global (L2-resident, 1KB coalesced per load) ----
    const short* __restrict__ bbase = Bf + (long)bk * (48 * 512) + l * 8;
    #pragma unroll
    for (int kc = 0; kc < 2; ++kc) {
      #pragma unroll
      for (int nt = 0; nt < 12; ++nt) {
        const short8 bh = *reinterpret_cast<const short8*>(bbase + ((kc * 12 + nt) * 2 + 0) * 512);
        const short8 bl = *reinterpret_cast<const short8*>(bbase + ((kc * 12 + nt) * 2 + 1) * 512);
        #pragma unroll
        for (int mf = 0; mf < 2; ++mf) {
          acc[mf][nt] = __builtin_amdgcn_mfma_f32_16x16x32_bf16(ah[kc][mf], bh, acc[mf][nt], 0, 0, 0);
          acc[mf][nt] = __builtin_amdgcn_mfma_f32_16x16x32_bf16(al[kc][mf], bh, acc[mf][nt], 0, 0, 0);
          acc[mf][nt] = __builtin_amdgcn_mfma_f32_16x16x32_bf16(ah[kc][mf], bl, acc[mf][nt], 0, 0, 0);
        }
      }
    }
  }

  // epilogue: C/D layout col = lane&15, row = (lane>>4)*4 + reg
  #pragma unroll
  for (int mf = 0; mf < 2; ++mf) {
    const long rbase = blkrow + w * 32 + mf * 16 + g * 4;
    #pragma unroll
    for (int nt = 0; nt < 12; ++nt) {
      const int col = nt * 16 + lr;
      const float bb = bih[col];
      #pragma unroll
      for (int i = 0; i < 4; ++i)
        gi[(rbase + i) * 192 + col] = acc[mf][nt][i] + bb;
    }
  }
}

// ---------------- recurrence over K=20 using precomputed gi ----------------
// wave owns 4 seqs, lane = hidden unit; h in regs, broadcast via readlane.
__global__ __launch_bounds__(256) void k_recur(
    const float* __restrict__ gi, const float* __restrict__ WhhT,
    const float* __restrict__ bhh, float* __restrict__ rout, const int seq0)
{
  __shared__ float wsh[64][192];   // 48 KB, [k2][gate*64+unit]
  const int tid = threadIdx.x;
  for (int idx = tid; idx < 64 * 192; idx += 256) wsh[idx / 192][idx % 192] = WhhT[idx];
  __syncthreads();

  const int w = tid >> 6, l = tid & 63;
  const int lseq0 = blockIdx.x * 16 + w * 4;
  const float bR = bhh[l], bZ = bhh[64 + l], bN = bhh[128 + l];
  float h[4] = {0.f, 0.f, 0.f, 0.f};
  float rsum[4] = {0.f, 0.f, 0.f, 0.f};

  for (int k = 0; k < K; ++k) {
    float aR[4], aZ[4], aN[4], gR[4], gZ[4], gN[4];
    #pragma unroll
    for (int ii = 0; ii < 4; ++ii) {
      const long row = ((long)(lseq0 + ii) * K + k) * 192;
      gR[ii] = gi[row + l]; gZ[ii] = gi[row + 64 + l]; gN[ii] = gi[row + 128 + l];
      aR[ii] = bR; aZ[ii] = bZ; aN[ii] = bN;
    }
    #pragma unroll 16
    for (int k2 = 0; k2 < H; ++k2) {
      const float wr = wsh[k2][l], wz = wsh[k2][64 + l], wn = wsh[k2][128 + l];
      #pragma unroll
      for (int ii = 0; ii < 4; ++ii) {
        const float hk = rdlane(h[ii], k2);
        aR[ii] += wr * hk; aZ[ii] += wz * hk; aN[ii] += wn * hk;
      }
    }
    #pragma unroll
    for (int ii = 0; ii < 4; ++ii) {
      const float r = sigm(gR[ii] + aR[ii]);
      const float z = sigm(gZ[ii] + aZ[ii]);
      const float nn = tanhf(gN[ii] + r * aN[ii]);
      h[ii] = (1.f - z) * nn + z * h[ii];
      rsum[ii] += h[ii];
    }
  }
  #pragma unroll
  for (int ii = 0; ii < 4; ++ii) {
    const int gseq = seq0 + lseq0 + ii;
    const int tt = gseq / N, n = gseq % N;
    rout[(n * T + tt) * H + l] = rsum[ii];
  }
}

// ---------------- GRU over p, q = sum_t h ----------------
__global__ __launch_bounds__(256) void k_gru_p(
    const float* __restrict__ p, const float* __restrict__ Wih,
    const float* __restrict__ Whh, const float* __restrict__ bih,
    const float* __restrict__ bhh, float* __restrict__ q)
{
  __shared__ float hs[4][H];
  const int w = threadIdx.x >> 6, lane = threadIdx.x & 63;
  const int n = blockIdx.x * 4 + w;
  hs[w][lane] = 0.f;
  float h = 0.f, qs = 0.f;
  __syncthreads();
  for (int t = 0; t < T; ++t) {
    const float x0 = p[n * (T * 3) + t * 3 + 0];
    const float x1 = p[n * (T * 3) + t * 3 + 1];
    const float x2 = p[n * (T * 3) + t * 3 + 2];
    float gr = bih[lane]     + Wih[lane * 3] * x0       + Wih[lane * 3 + 1] * x1       + Wih[lane * 3 + 2] * x2;
    float gz = bih[64 + lane]  + Wih[(64 + lane) * 3] * x0  + Wih[(64 + lane) * 3 + 1] * x1  + Wih[(64 + lane) * 3 + 2] * x2;
    float gn = bih[128 + lane] + Wih[(128 + lane) * 3] * x0 + Wih[(128 + lane) * 3 + 1] * x1 + Wih[(128 + lane) * 3 + 2] * x2;
    float hr = bhh[lane], hz = bhh[64 + lane], hn = bhh[128 + lane];
    #pragma unroll 8
    for (int k2 = 0; k2 < H; ++k2) {
      const float hk = hs[w][k2];
      hr += Whh[lane * H + k2] * hk;
      hz += Whh[(64 + lane) * H + k2] * hk;
      hn += Whh[(128 + lane) * H + k2] * hk;
    }
    const float r = sigm(gr + hr), z = sigm(gz + hz);
    const float nn = tanhf(gn + r * hn);
    h = (1.f - z) * nn + z * h;
    qs += h;
    __syncthreads();
    hs[w][lane] = h;
    __syncthreads();
  }
  q[n * H + lane] = qs;
}

// ---------------- GRU over r, c = sum_t h ----------------
__global__ __launch_bounds__(256) void k_gru_s(
    const float* __restrict__ rin, const float* __restrict__ Wih,
    const float* __restrict__ Whh, const float* __restrict__ bih,
    const float* __restrict__ bhh, float* __restrict__ c)
{
  __shared__ float hs[4][H];
  __shared__ float xsh[4][H];
  const int w = threadIdx.x >> 6, lane = threadIdx.x & 63;
  const int n = blockIdx.x * 4 + w;
  hs[w][lane] = 0.f;
  float h = 0.f, cs = 0.f;
  __syncthreads();
  for (int t = 0; t < T; ++t) {
    xsh[w][lane] = rin[(n * T + t) * H + lane];
    __syncthreads();
    float gr = bih[lane], gz = bih[64 + lane], gn = bih[128 + lane];
    float hr = bhh[lane], hz = bhh[64 + lane], hn = bhh[128 + lane];
    #pragma unroll 8
    for (int k2 = 0; k2 < H; ++k2) {
      const float xk = xsh[w][k2];
      const float hk = hs[w][k2];
      gr += Wih[lane * H + k2] * xk;  gz += Wih[(64 + lane) * H + k2] * xk;  gn += Wih[(128 + lane) * H + k2] * xk;
      hr += Whh[lane * H + k2] * hk;  hz += Whh[(64 + lane) * H + k2] * hk;  hn += Whh[(128 + lane) * H + k2] * hk;
    }
    const float r = sigm(gr + hr), z = sigm(gz + hz);
    const float nn = tanhf(gn + r * hn);
    h = (1.f - z) * nn + z * h;
    cs += h;
    __syncthreads();
    hs[w][lane] = h;
    __syncthreads();
  }
  c[n * H + lane] = cs;
}

// ---------------- bilinear blend + relu ----------------
__global__ __launch_bounds__(256) void k_blend(
    const float* __restrict__ q, const float* __restrict__ c,
    const float* __restrict__ W, const float* __restrict__ b,
    float* __restrict__ xout)
{
  __shared__ alignas(16) float qs[4][H];
  __shared__ alignas(16) float cs[4][H];
  const int nl = threadIdx.x >> 6, o = threadIdx.x & 63;
  const int n = blockIdx.x * 4 + nl;
  qs[nl][o] = q[n * H + o];
  cs[nl][o] = c[n * H + o];
  __syncthreads();
  float acc = b[o];
  const float4* __restrict__ W4 = reinterpret_cast<const float4*>(W) + o * (H * H / 4);
  const float4* c4 = reinterpret_cast<const float4*>(&cs[nl][0]);
  for (int i = 0; i < H; ++i) {
    float part = 0.f;
    #pragma unroll 4
    for (int j4 = 0; j4 < H / 4; ++j4) {
      const float4 wv = W4[i * (H / 4) + j4];
      const float4 cv = c4[j4];
      part += wv.x * cv.x + wv.y * cv.y + wv.z * cv.z + wv.w * cv.w;
    }
    acc += qs[nl][i] * part;
  }
  xout[n * H + o] = fmaxf(acc, 0.f);
}

// ---------------- adjacency compaction ----------------
__global__ __launch_bounds__(256) void k_compact(
    const float* __restrict__ adj, int* __restrict__ nbr, int* __restrict__ deg)
{
  const int w = threadIdx.x >> 6, lane = threadIdx.x & 63;
  const int i = blockIdx.x * 4 + w;
  int base = 0;
  for (int j0 = 0; j0 < N; j0 += 64) {
    const float v = adj[(long)i * N + j0 + lane];
    const unsigned long long mask = __ballot(v > 0.f);
    const int pre = __popcll(mask & ((1ull << lane) - 1ull));
    if (v > 0.f && base + pre < CAP) nbr[i * CAP + base + pre] = j0 + lane;
    base += __popcll(mask);
  }
  if (lane == 0) deg[i] = base < CAP ? base : CAP;
}

// ---------------- GAT precompute Wh, s1, s2 (round-3 version) ----------------
__global__ __launch_bounds__(256) void k_gat_pre(
    const float* __restrict__ x, const float* __restrict__ W,
    const float* __restrict__ a, const int F,
    float* __restrict__ Wh, float* __restrict__ s1, float* __restrict__ s2)
{
  const int nl = threadIdx.x >> 6, o = threadIdx.x & 63;
  const int n = blockIdx.x * 4 + nl;
  const int u = blockIdx.y;
  const float* __restrict__ Wu = W + (long)u * F * 64;
  const float* __restrict__ xn = x + (long)n * F;
  float acc = 0.f;
  #pragma unroll 8
  for (int f = 0; f < F; ++f) acc += xn[f] * Wu[f * 64 + o];
  Wh[((long)u * N + n) * 64 + o] = acc;
  float p1 = acc * a[u * 128 + o];
  float p2 = acc * a[u * 128 + 64 + o];
  #pragma unroll
  for (int d = 32; d > 0; d >>= 1) { p1 += __shfl_xor(p1, d, 64); p2 += __shfl_xor(p2, d, 64); }
  if (o == 0) { s1[u * N + n] = p1; s2[u * N + n] = p2; }
}

// ---------------- GAT attention (round-3 two-phase version) ----------------
__global__ __launch_bounds__(256) void k_gat_attn(
    const float* __restrict__ Wh, const float* __restrict__ s1,
    const float* __restrict__ s2, const int* __restrict__ nbr,
    const int* __restrict__ deg, const int mode, float* __restrict__ out)
{
  __shared__ float ew[4][CAP];
  __shared__ int nb[4][CAP];
  const int w = threadIdx.x >> 6, lane = threadIdx.x & 63;
  const int row = blockIdx.x * 4 + w;
  const int u = row >> 11;
  const int i = row & (N - 1);
  const int d = deg[i];
  const float su = s1[u * N + i];
  float mx = -1e30f;
  for (int t = lane; t < d; t += 64) {
    const int j = nbr[i * CAP + t];
    float e = su + s2[u * N + j];
    e = e > 0.f ? e : SLOPE * e;
    ew[w][t] = e; nb[w][t] = j;
    mx = fmaxf(mx, e);
  }
  #pragma unroll
  for (int dd = 32; dd > 0; dd >>= 1) mx = fmaxf(mx, __shfl_xor(mx, dd, 64));
  float sm = 0.f;
  for (int t = lane; t < d; t += 64) {
    const float ex = expf(ew[w][t] - mx);
    ew[w][t] = ex;
    sm += ex;
  }
  #pragma unroll
  for (int dd = 32; dd > 0; dd >>= 1) sm += __shfl_xor(sm, dd, 64);
  __syncthreads();
  const float inv = 1.f / sm;
  float acc = 0.f;
  for (int t = 0; t < d; ++t) {
    const float att = ew[w][t];
    const int j = nb[w][t];
    acc += att * Wh[((long)u * N + j) * 64 + lane];
  }
  acc *= inv;
  float val;
  if (mode == 0) val = acc > 0.f ? acc : (expf(acc) - 1.f);
  else           val = 1.f / (1.f + expf(-acc));
  out[(long)i * (U * 64) + u * 64 + lane] = val;
}

// ---------------- final projection + sigmoid ----------------
__global__ __launch_bounds__(256) void k_final(
    const float* __restrict__ nz, const float* __restrict__ fw,
    const float* __restrict__ fb, float* __restrict__ out)
{
  const int w = threadIdx.x >> 6, lane = threadIdx.x & 63;
  const int n = blockIdx.x * 4 + w;
  float p = 0.f;
  #pragma unroll
  for (int f = lane; f < 512; f += 64) p += nz[(long)n * 512 + f] * fw[f];
  #pragma unroll
  for (int d = 32; d > 0; d >>= 1) p += __shfl_xor(p, d, 64);
  if (lane == 0) out[n] = 1.f / (1.f + expf(-(p + fb[0])));
}

}  // namespace

extern "C" void kernel_launch(void* const* d_in, const int* in_sizes, int n_in,
                              void* d_out, int out_size, void* d_ws, size_t ws_size,
                              hipStream_t stream)
{
  const float* p     = (const float*)d_in[0];
  const float* m     = (const float*)d_in[1];
  const float* adj   = (const float*)d_in[2];
  const float* Wih_p = (const float*)d_in[3];
  const float* Whh_p = (const float*)d_in[4];
  const float* bih_p = (const float*)d_in[5];
  const float* bhh_p = (const float*)d_in[6];
  const float* Wih_m = (const float*)d_in[7];
  const float* Whh_m = (const float*)d_in[8];
  const float* bih_m = (const float*)d_in[9];
  const float* bhh_m = (const float*)d_in[10];
  const float* Wih_s = (const float*)d_in[11];
  const float* Whh_s = (const float*)d_in[12];
  const float* bih_s = (const float*)d_in[13];
  const float* bhh_s = (const float*)d_in[14];
  // d_in[15..23]: lin-attn weights — unused (softmax over size-1 axis == 1)
  const float* blend_W = (const float*)d_in[24];
  const float* blend_b = (const float*)d_in[25];
  const float* g1W = (const float*)d_in[26];
  const float* g1a = (const float*)d_in[27];
  const float* g2W = (const float*)d_in[28];
  const float* g2a = (const float*)d_in[29];
  const float* finW = (const float*)d_in[30];
  const float* finb = (const float*)d_in[31];

  float* ws = (float*)d_ws;
  float* q    = ws;                  // N*H
  float* rr   = q + N * H;           // N*T*H
  float* c    = rr + N * T * H;      // N*H
  float* xb   = c + N * H;           // N*H
  float* Wh1  = xb + N * H;          // U*N*64
  float* s1a  = Wh1 + U * N * 64;    // U*N
  float* s2a  = s1a + U * N;         // U*N
  float* z    = s2a + U * N;         // N*512
  float* Wh2  = z + (long)N * 512;   // U*N*64
  float* s1b  = Wh2 + U * N * 64;    // U*N
  float* s2b  = s1b + U * N;         // U*N
  float* nz   = s2b + U * N;         // N*512
  int*   nbr  = (int*)(nz + (long)N * 512);   // N*CAP ints
  int*   deg  = nbr + (long)N * CAP;          // N ints
  short* Bf   = (short*)(deg + N);            // 8*48*512 shorts (384 KB)
  float* WhhT = (float*)(Bf + 8 * 48 * 512);  // 64*192 fp32
  float* gi   = WhhT + 64 * 192;              // chunked

  // chunk the gi buffer to whatever scratch remains (deterministic in ws_size)
  const long avail = (long)(ws_size / 4) - (gi - ws);
  const long total_seqs = (long)T * N;                       // 10240
  long chunk = (avail / ((long)K * 192) / 32) * 32;          // mult of 32 seqs (640 rows)
  if (chunk > total_seqs) chunk = total_seqs;
  if (chunk < 32) chunk = 32;

  k_prep<<<64, 256, 0, stream>>>(Wih_m, Whh_m, Bf, WhhT);
  k_gru_p<<<N / 4, 256, 0, stream>>>(p, Wih_p, Whh_p, bih_p, bhh_p, q);
  for (long s0 = 0; s0 < total_seqs; s0 += chunk) {
    const long cs = (total_seqs - s0) < chunk ? (total_seqs - s0) : chunk;
    const long rows = cs * K;                                // multiple of 128: 640*x
    k_gemm<<<(int)(rows / 128), 256, 0, stream>>>(m, Bf, bih_m, gi, s0 * K);
    k_recur<<<(int)(cs / 16), 256, 0, stream>>>(gi, WhhT, bhh_m, rr, (int)s0);
  }
  k_gru_s<<<N / 4, 256, 0, stream>>>(rr, Wih_s, Whh_s, bih_s, bhh_s, c);
  k_blend<<<N / 4, 256, 0, stream>>>(q, c, blend_W, blend_b, xb);
  k_compact<<<N / 4, 256, 0, stream>>>(adj, nbr, deg);
  k_gat_pre<<<dim3(N / 4, U), 256, 0, stream>>>(xb, g1W, g1a, 64, Wh1, s1a, s2a);
  k_gat_attn<<<(U * N) / 4, 256, 0, stream>>>(Wh1, s1a, s2a, nbr, deg, 0, z);
  k_gat_pre<<<dim3(N / 4, U), 256, 0, stream>>>(z, g2W, g2a, 512, Wh2, s1b, s2b);
  k_gat_attn<<<(U * N) / 4, 256, 0, stream>>>(Wh2, s1b, s2b, nbr, deg, 1, nz);
  k_final<<<N / 4, 256, 0, stream>>>(nz, finW, finb, (float*)d_out);
}

// Round 6
// 680.894 us; speedup vs baseline: 1.7197x; 1.4943x over previous
//
#include <hip/hip_runtime.h>
#include <math.h>

namespace {

constexpr int T = 5, N = 2048, K = 20, E = 512;
constexpr int H = 64, U = 8;
constexpr int CAP = 512;           // max neighbors kept (measured mean ~103)
constexpr float SLOPE = 0.01f;

typedef __attribute__((ext_vector_type(8))) short short8;
typedef __attribute__((ext_vector_type(4))) float f32x4;

__device__ inline float sigm(float x) { return 1.0f / (1.0f + expf(-x)); }

// split fp32 -> bf16 hi + bf16 lo (truncation; x ~= hi+lo with rel err <= 2^-16)
__device__ inline void bsplit(float x, short& hi, short& lo) {
  unsigned u = __float_as_uint(x);
  hi = (short)(u >> 16);
  float r = x - __uint_as_float(u & 0xFFFF0000u);
  lo = (short)(__float_as_uint(r) >> 16);
}

__device__ inline float rdlane(float v, int lane) {
  return __int_as_float(__builtin_amdgcn_readlane(__float_as_int(v), lane));
}

// ---------------- prep: Wih_m fragments, WhhT, blend Wt2 ----------------
// Bf layout: frag f = ((bk*2+kc)*12 + nt)*2 + hl, each 512 shorts (1KB).
// inner offset = koct*128 + c16*8 + j ; element (o,k): o = nt*16+c16, k = bk*64+kc*32+koct*8+j
__global__ __launch_bounds__(256) void k_prep(
    const float* __restrict__ Wih, const float* __restrict__ Whh,
    const float* __restrict__ Wb,
    short* __restrict__ Bf, float* __restrict__ WhhT, float* __restrict__ Wt2)
{
  for (int idx = threadIdx.x + blockIdx.x * 256; idx < 192 * E; idx += 256 * 64) {
    const int o = idx >> 9, k = idx & 511;
    short hi, lo; bsplit(Wih[idx], hi, lo);
    const int bk = k >> 6, kc = (k >> 5) & 1, koct = (k >> 3) & 3, j = k & 7;
    const int nt = o >> 4, c16 = o & 15;
    const long f = ((long)(bk * 2 + kc) * 12 + nt) * 2;
    const int off = koct * 128 + c16 * 8 + j;
    Bf[f * 512 + off] = hi;
    Bf[(f + 1) * 512 + off] = lo;
  }
  for (int idx = threadIdx.x + blockIdx.x * 256; idx < 64 * 192; idx += 256 * 64) {
    const int k2 = idx / 192, row = idx % 192;
    WhhT[idx] = Whh[row * 64 + k2];
  }
  // blend W transpose: Wt2[((i*16+j4)*64+o)*4 + jr] = Wb[o][i][j4*4+jr]
  for (int idx = threadIdx.x + blockIdx.x * 256; idx < 64 * 64 * 64; idx += 256 * 64) {
    const int o = idx >> 12, rem = idx & 4095, i = rem >> 6, j = rem & 63;
    Wt2[((i * 16 + (j >> 2)) * 64 + o) * 4 + (j & 3)] = Wb[(o * 64 + i) * 64 + j];
  }
}

// ---------------- prep2: g2W -> fragment blocks for k_gemmW ----------------
// Bf2 index = ((cb*8 + bk))*16384 + ((kc*8+nt)*2+hl)*512 + koct*128 + c16*8 + j
// col = u*64+o: cb=col>>7, nt=(col>>4)&7, c16=col&15 ; k=f
__global__ __launch_bounds__(256) void k_prep2(
    const float* __restrict__ g2W, short* __restrict__ Bf2)
{
  for (int idx = threadIdx.x + blockIdx.x * 256; idx < 8 * 512 * 64; idx += 256 * 128) {
    const int u = idx >> 15, rem = idx & 32767, f = rem >> 6, o = rem & 63;
    short hi, lo; bsplit(g2W[idx], hi, lo);
    const int col = u * 64 + o;
    const int cb = col >> 7, nt = (col >> 4) & 7, c16 = col & 15;
    const int bk = f >> 6, kc = (f >> 5) & 1, koct = (f >> 3) & 3, j = f & 7;
    const long base = ((long)(cb * 8 + bk)) * 16384 + ((kc * 8 + nt) * 2) * 512
                      + koct * 128 + c16 * 8 + j;
    Bf2[base] = hi;
    Bf2[base + 512] = lo;
  }
}

// ---------------- gi GEMM: [rows,512] x [512,192], bf16 MFMA split-precision ------
// 256 thr / 4 waves; M=128/block (mf=2), N=192, BK=64.
// B: global_load_lds once per block per bk (zero redundancy); A: global->reg.
__global__ __launch_bounds__(256, 2) void k_gemm(
    const float* __restrict__ m, const short* __restrict__ Bf,
    const float* __restrict__ bih, float* __restrict__ gi, const long row0)
{
  __shared__ alignas(16) short Bc[48 * 512];   // 48 KB
  const int tid = threadIdx.x, w = tid >> 6, l = tid & 63;
  const int lr = l & 15, g = l >> 4;
  const long blkrow = (long)blockIdx.x * 128;

  f32x4 acc[2][12];
  #pragma unroll
  for (int mf = 0; mf < 2; ++mf)
    #pragma unroll
    for (int nt = 0; nt < 12; ++nt) acc[mf][nt] = (f32x4){0.f, 0.f, 0.f, 0.f};

  for (int bk = 0; bk < 8; ++bk) {
    const short* __restrict__ bsrc = Bf + (long)bk * 24576;
    #pragma unroll
    for (int i = 0; i < 12; ++i) {
      const int c = w + i * 4;
      __builtin_amdgcn_global_load_lds(
          (const __attribute__((address_space(1))) void*)(bsrc + c * 512 + l * 8),
          (__attribute__((address_space(3))) void*)(&Bc[c * 512]), 16, 0, 0);
    }
    short8 ah[2][2], al[2][2];
    #pragma unroll
    for (int kc = 0; kc < 2; ++kc)
      #pragma unroll
      for (int mf = 0; mf < 2; ++mf) {
        const long r = blkrow + w * 32 + mf * 16 + lr;
        const float* __restrict__ src = m + (row0 + r) * E + bk * 64 + kc * 32 + g * 8;
        const float4 v0 = *reinterpret_cast<const float4*>(src);
        const float4 v1 = *reinterpret_cast<const float4*>(src + 4);
        short h0,l0,h1,l1,h2,l2,h3,l3,h4,l4,h5,l5,h6,l6,h7,l7;
        bsplit(v0.x,h0,l0); bsplit(v0.y,h1,l1); bsplit(v0.z,h2,l2); bsplit(v0.w,h3,l3);
        bsplit(v1.x,h4,l4); bsplit(v1.y,h5,l5); bsplit(v1.z,h6,l6); bsplit(v1.w,h7,l7);
        ah[kc][mf] = (short8){h0,h1,h2,h3,h4,h5,h6,h7};
        al[kc][mf] = (short8){l0,l1,l2,l3,l4,l5,l6,l7};
      }
    __syncthreads();   // B staged

    #pragma unroll
    for (int kc = 0; kc < 2; ++kc) {
      #pragma unroll
      for (int nt = 0; nt < 12; ++nt) {
        const short8 bh = *reinterpret_cast<const short8*>(&Bc[((kc * 12 + nt) * 2 + 0) * 512 + l * 8]);
        const short8 bl = *reinterpret_cast<const short8*>(&Bc[((kc * 12 + nt) * 2 + 1) * 512 + l * 8]);
        #pragma unroll
        for (int mf = 0; mf < 2; ++mf) {
          acc[mf][nt] = __builtin_amdgcn_mfma_f32_16x16x32_bf16(ah[kc][mf], bh, acc[mf][nt], 0, 0, 0);
          acc[mf][nt] = __builtin_amdgcn_mfma_f32_16x16x32_bf16(al[kc][mf], bh, acc[mf][nt], 0, 0, 0);
          acc[mf][nt] = __builtin_amdgcn_mfma_f32_16x16x32_bf16(ah[kc][mf], bl, acc[mf][nt], 0, 0, 0);
        }
      }
    }
    __syncthreads();   // protect Bc
  }

  #pragma unroll
  for (int mf = 0; mf < 2; ++mf) {
    const long rbase = blkrow + w * 32 + mf * 16 + g * 4;
    #pragma unroll
    for (int nt = 0; nt < 12; ++nt) {
      const int col = nt * 16 + lr;
      const float bb = bih[col];
      #pragma unroll
      for (int i = 0; i < 4; ++i)
        gi[(rbase + i) * 192 + col] = acc[mf][nt][i] + bb;
    }
  }
}

// ---------------- generic MFMA GEMM for GAT layer-2: [2048,512]x[512,128/cb] ------
__global__ __launch_bounds__(256, 2) void k_gemmW(
    const float* __restrict__ x, const short* __restrict__ Bf2,
    float* __restrict__ Wh, const int nbk, const int strideA)
{
  __shared__ alignas(16) short Bc[32 * 512];   // 32 KB
  const int tid = threadIdx.x, w = tid >> 6, l = tid & 63;
  const int lr = l & 15, g = l >> 4;
  const long blkrow = (long)blockIdx.x * 128;
  const int cb = blockIdx.y;

  f32x4 acc[2][8];
  #pragma unroll
  for (int mf = 0; mf < 2; ++mf)
    #pragma unroll
    for (int nt = 0; nt < 8; ++nt) acc[mf][nt] = (f32x4){0.f, 0.f, 0.f, 0.f};

  for (int bk = 0; bk < nbk; ++bk) {
    const short* __restrict__ bsrc = Bf2 + ((long)cb * nbk + bk) * 16384;
    #pragma unroll
    for (int i = 0; i < 8; ++i) {
      const int c = w + i * 4;
      __builtin_amdgcn_global_load_lds(
          (const __attribute__((address_space(1))) void*)(bsrc + c * 512 + l * 8),
          (__attribute__((address_space(3))) void*)(&Bc[c * 512]), 16, 0, 0);
    }
    short8 ah[2][2], al[2][2];
    #pragma unroll
    for (int kc = 0; kc < 2; ++kc)
      #pragma unroll
      for (int mf = 0; mf < 2; ++mf) {
        const long r = blkrow + w * 32 + mf * 16 + lr;
        const float* __restrict__ src = x + r * strideA + bk * 64 + kc * 32 + g * 8;
        const float4 v0 = *reinterpret_cast<const float4*>(src);
        const float4 v1 = *reinterpret_cast<const float4*>(src + 4);
        short h0,l0,h1,l1,h2,l2,h3,l3,h4,l4,h5,l5,h6,l6,h7,l7;
        bsplit(v0.x,h0,l0); bsplit(v0.y,h1,l1); bsplit(v0.z,h2,l2); bsplit(v0.w,h3,l3);
        bsplit(v1.x,h4,l4); bsplit(v1.y,h5,l5); bsplit(v1.z,h6,l6); bsplit(v1.w,h7,l7);
        ah[kc][mf] = (short8){h0,h1,h2,h3,h4,h5,h6,h7};
        al[kc][mf] = (short8){l0,l1,l2,l3,l4,l5,l6,l7};
      }
    __syncthreads();

    #pragma unroll
    for (int kc = 0; kc < 2; ++kc) {
      #pragma unroll
      for (int nt = 0; nt < 8; ++nt) {
        const short8 bh = *reinterpret_cast<const short8*>(&Bc[((kc * 8 + nt) * 2 + 0) * 512 + l * 8]);
        const short8 bl = *reinterpret_cast<const short8*>(&Bc[((kc * 8 + nt) * 2 + 1) * 512 + l * 8]);
        #pragma unroll
        for (int mf = 0; mf < 2; ++mf) {
          acc[mf][nt] = __builtin_amdgcn_mfma_f32_16x16x32_bf16(ah[kc][mf], bh, acc[mf][nt], 0, 0, 0);
          acc[mf][nt] = __builtin_amdgcn_mfma_f32_16x16x32_bf16(al[kc][mf], bh, acc[mf][nt], 0, 0, 0);
          acc[mf][nt] = __builtin_amdgcn_mfma_f32_16x16x32_bf16(ah[kc][mf], bl, acc[mf][nt], 0, 0, 0);
        }
      }
    }
    __syncthreads();
  }

  #pragma unroll
  for (int mf = 0; mf < 2; ++mf) {
    const long rbase = blkrow + w * 32 + mf * 16 + g * 4;
    #pragma unroll
    for (int nt = 0; nt < 8; ++nt) {
      const int col = cb * 128 + nt * 16 + lr;
      const int u = col >> 6, o = col & 63;
      #pragma unroll
      for (int i = 0; i < 4; ++i)
        Wh[((long)u * N + (rbase + i)) * 64 + o] = acc[mf][nt][i];
    }
  }
}

// ---------------- recurrence: wave = 1 seq, lane = unit, Whh in REGISTERS --------
__global__ __launch_bounds__(256, 2) void k_recur(
    const float* __restrict__ gi, const float* __restrict__ WhhT,
    const float* __restrict__ bhh, float* __restrict__ rout, const int seq0)
{
  const int tid = threadIdx.x, w = tid >> 6, l = tid & 63;
  const int lseq = blockIdx.x * 4 + w;          // chunk-local seq
  float wr[64], wz[64], wn[64];
  #pragma unroll
  for (int k2 = 0; k2 < 64; ++k2) {
    wr[k2] = WhhT[k2 * 192 + l];
    wz[k2] = WhhT[k2 * 192 + 64 + l];
    wn[k2] = WhhT[k2 * 192 + 128 + l];
  }
  const float bR = bhh[l], bZ = bhh[64 + l], bN = bhh[128 + l];
  const float* __restrict__ grow = gi + (long)lseq * K * 192;
  float h = 0.f, rsum = 0.f;
  float gR = grow[l], gZ = grow[64 + l], gN = grow[128 + l];
  for (int k = 0; k < K; ++k) {
    float nR = 0.f, nZ = 0.f, nN = 0.f;
    if (k + 1 < K) {
      const int off = (k + 1) * 192;
      nR = grow[off + l]; nZ = grow[off + 64 + l]; nN = grow[off + 128 + l];
    }
    float aR = bR, aZ = bZ, aN = bN;
    #pragma unroll
    for (int k2 = 0; k2 < 64; ++k2) {
      const float hk = rdlane(h, k2);
      aR += wr[k2] * hk; aZ += wz[k2] * hk; aN += wn[k2] * hk;
    }
    const float r = sigm(gR + aR);
    const float z = sigm(gZ + aZ);
    const float nn = tanhf(gN + r * aN);
    h = (1.f - z) * nn + z * h;
    rsum += h;
    gR = nR; gZ = nZ; gN = nN;
  }
  const int gseq = seq0 + lseq;
  const int tt = gseq / N, n = gseq % N;
  rout[(n * T + tt) * H + l] = rsum;
}

// ---------------- GRU over p, q = sum_t h ----------------
__global__ __launch_bounds__(256) void k_gru_p(
    const float* __restrict__ p, const float* __restrict__ Wih,
    const float* __restrict__ Whh, const float* __restrict__ bih,
    const float* __restrict__ bhh, float* __restrict__ q)
{
  __shared__ float hs[4][H];
  const int w = threadIdx.x >> 6, lane = threadIdx.x & 63;
  const int n = blockIdx.x * 4 + w;
  hs[w][lane] = 0.f;
  float h = 0.f, qs = 0.f;
  __syncthreads();
  for (int t = 0; t < T; ++t) {
    const float x0 = p[n * (T * 3) + t * 3 + 0];
    const float x1 = p[n * (T * 3) + t * 3 + 1];
    const float x2 = p[n * (T * 3) + t * 3 + 2];
    float gr = bih[lane]     + Wih[lane * 3] * x0       + Wih[lane * 3 + 1] * x1       + Wih[lane * 3 + 2] * x2;
    float gz = bih[64 + lane]  + Wih[(64 + lane) * 3] * x0  + Wih[(64 + lane) * 3 + 1] * x1  + Wih[(64 + lane) * 3 + 2] * x2;
    float gn = bih[128 + lane] + Wih[(128 + lane) * 3] * x0 + Wih[(128 + lane) * 3 + 1] * x1 + Wih[(128 + lane) * 3 + 2] * x2;
    float hr = bhh[lane], hz = bhh[64 + lane], hn = bhh[128 + lane];
    #pragma unroll 8
    for (int k2 = 0; k2 < H; ++k2) {
      const float hk = hs[w][k2];
      hr += Whh[lane * H + k2] * hk;
      hz += Whh[(64 + lane) * H + k2] * hk;
      hn += Whh[(128 + lane) * H + k2] * hk;
    }
    const float r = sigm(gr + hr), z = sigm(gz + hz);
    const float nn = tanhf(gn + r * hn);
    h = (1.f - z) * nn + z * h;
    qs += h;
    __syncthreads();
    hs[w][lane] = h;
    __syncthreads();
  }
  q[n * H + lane] = qs;
}

// ---------------- GRU over r, c = sum_t h ----------------
__global__ __launch_bounds__(256) void k_gru_s(
    const float* __restrict__ rin, const float* __restrict__ Wih,
    const float* __restrict__ Whh, const float* __restrict__ bih,
    const float* __restrict__ bhh, float* __restrict__ c)
{
  __shared__ float hs[4][H];
  __shared__ float xsh[4][H];
  const int w = threadIdx.x >> 6, lane = threadIdx.x & 63;
  const int n = blockIdx.x * 4 + w;
  hs[w][lane] = 0.f;
  float h = 0.f, cs = 0.f;
  __syncthreads();
  for (int t = 0; t < T; ++t) {
    xsh[w][lane] = rin[(n * T + t) * H + lane];
    __syncthreads();
    float gr = bih[lane], gz = bih[64 + lane], gn = bih[128 + lane];
    float hr = bhh[lane], hz = bhh[64 + lane], hn = bhh[128 + lane];
    #pragma unroll 8
    for (int k2 = 0; k2 < H; ++k2) {
      const float xk = xsh[w][k2];
      const float hk = hs[w][k2];
      gr += Wih[lane * H + k2] * xk;  gz += Wih[(64 + lane) * H + k2] * xk;  gn += Wih[(128 + lane) * H + k2] * xk;
      hr += Whh[lane * H + k2] * hk;  hz += Whh[(64 + lane) * H + k2] * hk;  hn += Whh[(128 + lane) * H + k2] * hk;
    }
    const float r = sigm(gr + hr), z = sigm(gz + hz);
    const float nn = tanhf(gn + r * hn);
    h = (1.f - z) * nn + z * h;
    cs += h;
    __syncthreads();
    hs[w][lane] = h;
    __syncthreads();
  }
  c[n * H + lane] = cs;
}

// ---------------- bilinear blend + relu (transposed W, 8 n per block) -----------
__global__ __launch_bounds__(256) void k_blend(
    const float* __restrict__ q, const float* __restrict__ c,
    const float* __restrict__ Wt2, const float* __restrict__ b,
    float* __restrict__ xout)
{
  __shared__ float qs[8][64];
  __shared__ alignas(16) float cs[8][64];
  const int tid = threadIdx.x;
  const int o = tid & 63, grp = tid >> 6;
  const int n0 = blockIdx.x * 8;
  for (int idx = tid; idx < 512; idx += 256) {
    qs[idx >> 6][idx & 63] = q[(n0 + (idx >> 6)) * 64 + (idx & 63)];
    cs[idx >> 6][idx & 63] = c[(n0 + (idx >> 6)) * 64 + (idx & 63)];
  }
  __syncthreads();
  const int na = grp * 2, nb = na + 1;
  float acca = b[o], accb = b[o];
  const float4* __restrict__ W4 = reinterpret_cast<const float4*>(Wt2);
  const float4* ca4 = reinterpret_cast<const float4*>(&cs[na][0]);
  const float4* cb4 = reinterpret_cast<const float4*>(&cs[nb][0]);
  for (int i = 0; i < 64; ++i) {
    float pa = 0.f, pb = 0.f;
    #pragma unroll
    for (int j4 = 0; j4 < 16; ++j4) {
      const float4 wv = W4[(i * 16 + j4) * 64 + o];
      const float4 va = ca4[j4], vb = cb4[j4];
      pa += wv.x * va.x + wv.y * va.y + wv.z * va.z + wv.w * va.w;
      pb += wv.x * vb.x + wv.y * vb.y + wv.z * vb.z + wv.w * vb.w;
    }
    acca += qs[na][i] * pa;
    accb += qs[nb][i] * pb;
  }
  xout[(n0 + na) * 64 + o] = fmaxf(acca, 0.f);
  xout[(n0 + nb) * 64 + o] = fmaxf(accb, 0.f);
}

// ---------------- adjacency compaction ----------------
__global__ __launch_bounds__(256) void k_compact(
    const float* __restrict__ adj, int* __restrict__ nbr, int* __restrict__ deg)
{
  const int w = threadIdx.x >> 6, lane = threadIdx.x & 63;
  const int i = blockIdx.x * 4 + w;
  int base = 0;
  for (int j0 = 0; j0 < N; j0 += 64) {
    const float v = adj[(long)i * N + j0 + lane];
    const unsigned long long mask = __ballot(v > 0.f);
    const int pre = __popcll(mask & ((1ull << lane) - 1ull));
    if (v > 0.f && base + pre < CAP) nbr[i * CAP + base + pre] = j0 + lane;
    base += __popcll(mask);
  }
  if (lane == 0) deg[i] = base < CAP ? base : CAP;
}

// ---------------- GAT layer-1 precompute (F=64) ----------------
__global__ __launch_bounds__(256) void k_gat_pre(
    const float* __restrict__ x, const float* __restrict__ W,
    const float* __restrict__ a, const int F,
    float* __restrict__ Wh, float* __restrict__ s1, float* __restrict__ s2)
{
  const int nl = threadIdx.x >> 6, o = threadIdx.x & 63;
  const int n = blockIdx.x * 4 + nl;
  const int u = blockIdx.y;
  const float* __restrict__ Wu = W + (long)u * F * 64;
  const float* __restrict__ xn = x + (long)n * F;
  float acc = 0.f;
  #pragma unroll 8
  for (int f = 0; f < F; ++f) acc += xn[f] * Wu[f * 64 + o];
  Wh[((long)u * N + n) * 64 + o] = acc;
  float p1 = acc * a[u * 128 + o];
  float p2 = acc * a[u * 128 + 64 + o];
  #pragma unroll
  for (int d = 32; d > 0; d >>= 1) { p1 += __shfl_xor(p1, d, 64); p2 += __shfl_xor(p2, d, 64); }
  if (o == 0) { s1[u * N + n] = p1; s2[u * N + n] = p2; }
}

// ---------------- s1/s2 from precomputed Wh (layer 2) ----------------
__global__ __launch_bounds__(256) void k_s12(
    const float* __restrict__ Wh, const float* __restrict__ a,
    float* __restrict__ s1, float* __restrict__ s2)
{
  const int nl = threadIdx.x >> 6, o = threadIdx.x & 63;
  const int n = blockIdx.x * 4 + nl, u = blockIdx.y;
  const float acc = Wh[((long)u * N + n) * 64 + o];
  float p1 = acc * a[u * 128 + o];
  float p2 = acc * a[u * 128 + 64 + o];
  #pragma unroll
  for (int d = 32; d > 0; d >>= 1) { p1 += __shfl_xor(p1, d, 64); p2 += __shfl_xor(p2, d, 64); }
  if (o == 0) { s1[u * N + n] = p1; s2[u * N + n] = p2; }
}

// ---------------- GAT attention (two-phase, compacted) ----------------
__global__ __launch_bounds__(256) void k_gat_attn(
    const float* __restrict__ Wh, const float* __restrict__ s1,
    const float* __restrict__ s2, const int* __restrict__ nbr,
    const int* __restrict__ deg, const int mode, float* __restrict__ out)
{
  __shared__ float ew[4][CAP];
  __shared__ int nb[4][CAP];
  const int w = threadIdx.x >> 6, lane = threadIdx.x & 63;
  const int row = blockIdx.x * 4 + w;
  const int u = row >> 11;
  const int i = row & (N - 1);
  const int d = deg[i];
  const float su = s1[u * N + i];
  float mx = -1e30f;
  for (int t = lane; t < d; t += 64) {
    const int j = nbr[i * CAP + t];
    float e = su + s2[u * N + j];
    e = e > 0.f ? e : SLOPE * e;
    ew[w][t] = e; nb[w][t] = j;
    mx = fmaxf(mx, e);
  }
  #pragma unroll
  for (int dd = 32; dd > 0; dd >>= 1) mx = fmaxf(mx, __shfl_xor(mx, dd, 64));
  float sm = 0.f;
  for (int t = lane; t < d; t += 64) {
    const float ex = expf(ew[w][t] - mx);
    ew[w][t] = ex;
    sm += ex;
  }
  #pragma unroll
  for (int dd = 32; dd > 0; dd >>= 1) sm += __shfl_xor(sm, dd, 64);
  __syncthreads();
  const float inv = 1.f / sm;
  float acc = 0.f;
  for (int t = 0; t < d; ++t) {
    const float att = ew[w][t];
    const int j = nb[w][t];
    acc += att * Wh[((long)u * N + j) * 64 + lane];
  }
  acc *= inv;
  float val;
  if (mode == 0) val = acc > 0.f ? acc : (expf(acc) - 1.f);
  else           val = 1.f / (1.f + expf(-acc));
  out[(long)i * (U * 64) + u * 64 + lane] = val;
}

// ---------------- final projection + sigmoid ----------------
__global__ __launch_bounds__(256) void k_final(
    const float* __restrict__ nz, const float* __restrict__ fw,
    const float* __restrict__ fb, float* __restrict__ out)
{
  const int w = threadIdx.x >> 6, lane = threadIdx.x & 63;
  const int n = blockIdx.x * 4 + w;
  float p = 0.f;
  #pragma unroll
  for (int f = lane; f < 512; f += 64) p += nz[(long)n * 512 + f] * fw[f];
  #pragma unroll
  for (int d = 32; d > 0; d >>= 1) p += __shfl_xor(p, d, 64);
  if (lane == 0) out[n] = 1.f / (1.f + expf(-(p + fb[0])));
}

}  // namespace

extern "C" void kernel_launch(void* const* d_in, const int* in_sizes, int n_in,
                              void* d_out, int out_size, void* d_ws, size_t ws_size,
                              hipStream_t stream)
{
  const float* p     = (const float*)d_in[0];
  const float* m     = (const float*)d_in[1];
  const float* adj   = (const float*)d_in[2];
  const float* Wih_p = (const float*)d_in[3];
  const float* Whh_p = (const float*)d_in[4];
  const float* bih_p = (const float*)d_in[5];
  const float* bhh_p = (const float*)d_in[6];
  const float* Wih_m = (const float*)d_in[7];
  const float* Whh_m = (const float*)d_in[8];
  const float* bih_m = (const float*)d_in[9];
  const float* bhh_m = (const float*)d_in[10];
  const float* Wih_s = (const float*)d_in[11];
  const float* Whh_s = (const float*)d_in[12];
  const float* bih_s = (const float*)d_in[13];
  const float* bhh_s = (const float*)d_in[14];
  // d_in[15..23]: lin-attn weights — unused (softmax over size-1 axis == 1)
  const float* blend_W = (const float*)d_in[24];
  const float* blend_b = (const float*)d_in[25];
  const float* g1W = (const float*)d_in[26];
  const float* g1a = (const float*)d_in[27];
  const float* g2W = (const float*)d_in[28];
  const float* g2a = (const float*)d_in[29];
  const float* finW = (const float*)d_in[30];
  const float* finb = (const float*)d_in[31];

  float* ws = (float*)d_ws;
  float* q    = ws;                  // N*H
  float* rr   = q + N * H;           // N*T*H
  float* c    = rr + N * T * H;      // N*H
  float* xb   = c + N * H;           // N*H
  float* Wh1  = xb + N * H;          // U*N*64
  float* s1a  = Wh1 + U * N * 64;    // U*N
  float* s2a  = s1a + U * N;         // U*N
  float* z    = s2a + U * N;         // N*512
  float* Wh2  = z + (long)N * 512;   // U*N*64
  float* s1b  = Wh2 + U * N * 64;    // U*N
  float* s2b  = s1b + U * N;         // U*N
  float* nz   = s2b + U * N;         // N*512
  float* Wt2  = nz + (long)N * 512;  // 64*64*64
  int*   nbr  = (int*)(Wt2 + 64 * 64 * 64);   // N*CAP ints
  int*   deg  = nbr + (long)N * CAP;          // N ints
  short* Bf   = (short*)(deg + N);            // 8*48*512 shorts (384 KB)
  short* Bf2  = Bf + 8 * 48 * 512;            // 4*8*32*512 shorts (1 MB)
  float* WhhT = (float*)(Bf2 + 4 * 8 * 32 * 512);  // 64*192 fp32
  float* gi   = WhhT + 64 * 192;              // chunked

  // chunk the gi buffer to whatever scratch remains (deterministic in ws_size)
  const long avail = (long)(ws_size / 4) - (gi - ws);
  const long total_seqs = (long)T * N;                       // 10240
  long chunk = (avail / ((long)K * 192) / 32) * 32;          // mult of 32 seqs (640 rows)
  if (chunk > total_seqs) chunk = total_seqs;
  if (chunk < 32) chunk = 32;

  k_prep<<<64, 256, 0, stream>>>(Wih_m, Whh_m, blend_W, Bf, WhhT, Wt2);
  k_prep2<<<128, 256, 0, stream>>>(g2W, Bf2);
  k_gru_p<<<N / 4, 256, 0, stream>>>(p, Wih_p, Whh_p, bih_p, bhh_p, q);
  for (long s0 = 0; s0 < total_seqs; s0 += chunk) {
    const long cs = (total_seqs - s0) < chunk ? (total_seqs - s0) : chunk;
    const long rows = cs * K;                                // multiple of 640
    k_gemm<<<(int)(rows / 128), 256, 0, stream>>>(m, Bf, bih_m, gi, s0 * K);
    k_recur<<<(int)(cs / 4), 256, 0, stream>>>(gi, WhhT, bhh_m, rr, (int)s0);
  }
  k_gru_s<<<N / 4, 256, 0, stream>>>(rr, Wih_s, Whh_s, bih_s, bhh_s, c);
  k_blend<<<N / 8, 256, 0, stream>>>(q, c, Wt2, blend_b, xb);
  k_compact<<<N / 4, 256, 0, stream>>>(adj, nbr, deg);
  k_gat_pre<<<dim3(N / 4, U), 256, 0, stream>>>(xb, g1W, g1a, 64, Wh1, s1a, s2a);
  k_gat_attn<<<(U * N) / 4, 256, 0, stream>>>(Wh1, s1a, s2a, nbr, deg, 0, z);
  k_gemmW<<<dim3(N / 128, 4), 256, 0, stream>>>(z, Bf2, Wh2, 8, 512);
  k_s12<<<dim3(N / 4, U), 256, 0, stream>>>(Wh2, g2a, s1b, s2b);
  k_gat_attn<<<(U * N) / 4, 256, 0, stream>>>(Wh2, s1b, s2b, nbr, deg, 1, nz);
  k_final<<<N / 4, 256, 0, stream>>>(nz, finW, finb, (float*)d_out);
}

// Round 7
// 520.971 us; speedup vs baseline: 2.2475x; 1.3070x over previous
//
#include <hip/hip_runtime.h>
#include <math.h>

namespace {

constexpr int T = 5, N = 2048, K = 20, E = 512;
constexpr int H = 64, U = 8;
constexpr int CAP = 512;           // max neighbors kept (measured mean ~103)
constexpr float SLOPE = 0.01f;

typedef __attribute__((ext_vector_type(8))) short short8;
typedef __attribute__((ext_vector_type(4))) float f32x4;

__device__ inline float sigm(float x) { return 1.0f / (1.0f + expf(-x)); }

// split fp32 -> bf16 hi + bf16 lo (truncation; x ~= hi+lo with rel err <= 2^-16)
__device__ inline void bsplit(float x, short& hi, short& lo) {
  unsigned u = __float_as_uint(x);
  hi = (short)(u >> 16);
  float r = x - __uint_as_float(u & 0xFFFF0000u);
  lo = (short)(__float_as_uint(r) >> 16);
}

__device__ inline float rdlane(float v, int lane) {
  return __int_as_float(__builtin_amdgcn_readlane(__float_as_int(v), lane));
}

// ---------------- prep: fragment packs + transposes ----------------
// Fragment layout (192-col family, per 32-K step b): base = b*12288 +
//   (nt*2+hl)*512 + koct*128 + c16*8 + j ; element (o = nt*16+c16, k = b*32+koct*8+j)
__global__ __launch_bounds__(256) void k_prep(
    const float* __restrict__ WihM, const float* __restrict__ WhhM,
    const float* __restrict__ WihS, const float* __restrict__ WhhS,
    const float* __restrict__ WhhP, const float* __restrict__ Wb,
    short* __restrict__ BfM, short* __restrict__ BfS,
    float* __restrict__ WhhTm, float* __restrict__ WhhTs, float* __restrict__ WhhTp,
    float* __restrict__ Wt2)
{
  const int stride = 256 * 64;
  for (int idx = threadIdx.x + blockIdx.x * 256; idx < 192 * 512; idx += stride) {
    const int o = idx >> 9, k = idx & 511;
    short hi, lo; bsplit(WihM[idx], hi, lo);
    const long base = (long)(k >> 5) * 12288 + ((o >> 4) * 2) * 512
                    + ((k >> 3) & 3) * 128 + (o & 15) * 8 + (k & 7);
    BfM[base] = hi; BfM[base + 512] = lo;
  }
  for (int idx = threadIdx.x + blockIdx.x * 256; idx < 192 * 64; idx += stride) {
    const int o = idx >> 6, k = idx & 63;
    short hi, lo; bsplit(WihS[idx], hi, lo);
    const long base = (long)(k >> 5) * 12288 + ((o >> 4) * 2) * 512
                    + ((k >> 3) & 3) * 128 + (o & 15) * 8 + (k & 7);
    BfS[base] = hi; BfS[base + 512] = lo;
  }
  for (int idx = threadIdx.x + blockIdx.x * 256; idx < 64 * 192; idx += stride) {
    const int k2 = idx / 192, row = idx % 192;
    WhhTm[idx] = WhhM[row * 64 + k2];
    WhhTs[idx] = WhhS[row * 64 + k2];
    WhhTp[idx] = WhhP[row * 64 + k2];
  }
  // blend W transpose: Wt2[((i*16+j4)*64+o)*4 + jr] = Wb[o][i][j4*4+jr]
  for (int idx = threadIdx.x + blockIdx.x * 256; idx < 64 * 64 * 64; idx += stride) {
    const int o = idx >> 12, rem = idx & 4095, i = rem >> 6, j = rem & 63;
    Wt2[((i * 16 + (j >> 2)) * 64 + o) * 4 + (j & 3)] = Wb[(o * 64 + i) * 64 + j];
  }
}

// ---------------- prep2: [U][Ksz][64] weight -> 512-col fragment blocks ---------
// base = (cb*(Ksz/32) + b)*8192 + (ntc*2+hl)*512 + koct*128 + c16*8 + j
__global__ __launch_bounds__(256) void k_prep2(
    const float* __restrict__ src, short* __restrict__ dst, const int Ksz)
{
  const int nb32 = Ksz >> 5;
  const int total = 8 * Ksz * 64;
  for (int idx = threadIdx.x + blockIdx.x * 256; idx < total; idx += 256 * 128) {
    const int u = idx / (Ksz * 64), rem = idx - u * Ksz * 64;
    const int f = rem >> 6, o = rem & 63;
    short hi, lo; bsplit(src[idx], hi, lo);
    const int col = u * 64 + o;
    const int cb = col >> 7, ntc = (col >> 4) & 7, c16 = col & 15;
    const int b = f >> 5, koct = (f >> 3) & 3, j = f & 7;
    const long base = ((long)(cb * nb32 + b)) * 8192 + (ntc * 2) * 512
                    + koct * 128 + c16 * 8 + j;
    dst[base] = hi; dst[base + 512] = lo;
  }
}

// ---------------- 192-col GEMM: [rows,Ksz] x [Ksz,192] + bias, split-bf16 --------
// BK=32 double-buffered, stage-early 2-phase. 256 thr / 4 waves; M=128 (mf=2).
__global__ __launch_bounds__(256, 2) void k_gemm(
    const float* __restrict__ A, const short* __restrict__ Bf,
    const float* __restrict__ bias, float* __restrict__ out,
    const long row0, const int nb, const int strideA)
{
  __shared__ alignas(16) short Bc[2][24 * 512];   // 2 x 24 KB
  const int tid = threadIdx.x, w = tid >> 6, l = tid & 63;
  const int lr = l & 15, g = l >> 4;
  const long blkrow = (long)blockIdx.x * 128;

  f32x4 acc[2][12];
  #pragma unroll
  for (int mf = 0; mf < 2; ++mf)
    #pragma unroll
    for (int nt = 0; nt < 12; ++nt) acc[mf][nt] = (f32x4){0.f, 0.f, 0.f, 0.f};

  short8 ahC[2], alC[2], ahN[2], alN[2];

  auto LOADA = [&](int b, short8* ah, short8* al) {
    #pragma unroll
    for (int mf = 0; mf < 2; ++mf) {
      const long r = blkrow + w * 32 + mf * 16 + lr;
      const float* __restrict__ src = A + (row0 + r) * (long)strideA + b * 32 + g * 8;
      const float4 v0 = *reinterpret_cast<const float4*>(src);
      const float4 v1 = *reinterpret_cast<const float4*>(src + 4);
      short h0,l0,h1,l1,h2,l2,h3,l3,h4,l4,h5,l5,h6,l6,h7,l7;
      bsplit(v0.x,h0,l0); bsplit(v0.y,h1,l1); bsplit(v0.z,h2,l2); bsplit(v0.w,h3,l3);
      bsplit(v1.x,h4,l4); bsplit(v1.y,h5,l5); bsplit(v1.z,h6,l6); bsplit(v1.w,h7,l7);
      ah[mf] = (short8){h0,h1,h2,h3,h4,h5,h6,h7};
      al[mf] = (short8){l0,l1,l2,l3,l4,l5,l6,l7};
    }
  };
  auto STAGE = [&](int buf, int b) {
    const short* __restrict__ bsrc = Bf + (long)b * 12288;
    #pragma unroll
    for (int i = 0; i < 6; ++i) {
      const int c = w + i * 4;      // 24 x 1KB chunks
      __builtin_amdgcn_global_load_lds(
          (const __attribute__((address_space(1))) void*)(bsrc + c * 512 + l * 8),
          (__attribute__((address_space(3))) void*)(&Bc[buf][c * 512]), 16, 0, 0);
    }
  };

  LOADA(0, ahC, alC);
  STAGE(0, 0);
  __syncthreads();

  for (int b = 0; b < nb; ++b) {
    const bool more = (b + 1 < nb);
    if (more) { STAGE((b + 1) & 1, b + 1); LOADA(b + 1, ahN, alN); }
    const short* __restrict__ bcur = &Bc[b & 1][0];
    #pragma unroll
    for (int nt = 0; nt < 12; ++nt) {
      const short8 bh = *reinterpret_cast<const short8*>(bcur + (nt * 2 + 0) * 512 + l * 8);
      const short8 bl = *reinterpret_cast<const short8*>(bcur + (nt * 2 + 1) * 512 + l * 8);
      #pragma unroll
      for (int mf = 0; mf < 2; ++mf) {
        acc[mf][nt] = __builtin_amdgcn_mfma_f32_16x16x32_bf16(ahC[mf], bh, acc[mf][nt], 0, 0, 0);
        acc[mf][nt] = __builtin_amdgcn_mfma_f32_16x16x32_bf16(alC[mf], bh, acc[mf][nt], 0, 0, 0);
        acc[mf][nt] = __builtin_amdgcn_mfma_f32_16x16x32_bf16(ahC[mf], bl, acc[mf][nt], 0, 0, 0);
      }
    }
    __syncthreads();
    if (more) {
      #pragma unroll
      for (int mf = 0; mf < 2; ++mf) { ahC[mf] = ahN[mf]; alC[mf] = alN[mf]; }
    }
  }

  // epilogue: C/D layout col = lane&15, row = (lane>>4)*4 + reg
  #pragma unroll
  for (int mf = 0; mf < 2; ++mf) {
    const long rbase = blkrow + w * 32 + mf * 16 + g * 4;
    #pragma unroll
    for (int nt = 0; nt < 12; ++nt) {
      const int col = nt * 16 + lr;
      const float bb = bias[col];
      #pragma unroll
      for (int i = 0; i < 4; ++i)
        out[(rbase + i) * 192 + col] = acc[mf][nt][i] + bb;
    }
  }
}

// ---------------- 512-col GEMM (GAT Wh): [2048,Ksz] x [Ksz,128 per cb] ----------
__global__ __launch_bounds__(256, 2) void k_gemmW(
    const float* __restrict__ A, const short* __restrict__ Bf2,
    float* __restrict__ Wh, const int nb, const int strideA)
{
  __shared__ alignas(16) short Bc[2][16 * 512];   // 2 x 16 KB
  const int tid = threadIdx.x, w = tid >> 6, l = tid & 63;
  const int lr = l & 15, g = l >> 4;
  const long blkrow = (long)blockIdx.x * 128;
  const int cb = blockIdx.y;

  f32x4 acc[2][8];
  #pragma unroll
  for (int mf = 0; mf < 2; ++mf)
    #pragma unroll
    for (int nt = 0; nt < 8; ++nt) acc[mf][nt] = (f32x4){0.f, 0.f, 0.f, 0.f};

  short8 ahC[2], alC[2], ahN[2], alN[2];

  auto LOADA = [&](int b, short8* ah, short8* al) {
    #pragma unroll
    for (int mf = 0; mf < 2; ++mf) {
      const long r = blkrow + w * 32 + mf * 16 + lr;
      const float* __restrict__ src = A + r * (long)strideA + b * 32 + g * 8;
      const float4 v0 = *reinterpret_cast<const float4*>(src);
      const float4 v1 = *reinterpret_cast<const float4*>(src + 4);
      short h0,l0,h1,l1,h2,l2,h3,l3,h4,l4,h5,l5,h6,l6,h7,l7;
      bsplit(v0.x,h0,l0); bsplit(v0.y,h1,l1); bsplit(v0.z,h2,l2); bsplit(v0.w,h3,l3);
      bsplit(v1.x,h4,l4); bsplit(v1.y,h5,l5); bsplit(v1.z,h6,l6); bsplit(v1.w,h7,l7);
      ah[mf] = (short8){h0,h1,h2,h3,h4,h5,h6,h7};
      al[mf] = (short8){l0,l1,l2,l3,l4,l5,l6,l7};
    }
  };
  auto STAGE = [&](int buf, int b) {
    const short* __restrict__ bsrc = Bf2 + ((long)cb * nb + b) * 8192;
    #pragma unroll
    for (int i = 0; i < 4; ++i) {
      const int c = w + i * 4;      // 16 x 1KB chunks
      __builtin_amdgcn_global_load_lds(
          (const __attribute__((address_space(1))) void*)(bsrc + c * 512 + l * 8),
          (__attribute__((address_space(3))) void*)(&Bc[buf][c * 512]), 16, 0, 0);
    }
  };

  LOADA(0, ahC, alC);
  STAGE(0, 0);
  __syncthreads();

  for (int b = 0; b < nb; ++b) {
    const bool more = (b + 1 < nb);
    if (more) { STAGE((b + 1) & 1, b + 1); LOADA(b + 1, ahN, alN); }
    const short* __restrict__ bcur = &Bc[b & 1][0];
    #pragma unroll
    for (int nt = 0; nt < 8; ++nt) {
      const short8 bh = *reinterpret_cast<const short8*>(bcur + (nt * 2 + 0) * 512 + l * 8);
      const short8 bl = *reinterpret_cast<const short8*>(bcur + (nt * 2 + 1) * 512 + l * 8);
      #pragma unroll
      for (int mf = 0; mf < 2; ++mf) {
        acc[mf][nt] = __builtin_amdgcn_mfma_f32_16x16x32_bf16(ahC[mf], bh, acc[mf][nt], 0, 0, 0);
        acc[mf][nt] = __builtin_amdgcn_mfma_f32_16x16x32_bf16(alC[mf], bh, acc[mf][nt], 0, 0, 0);
        acc[mf][nt] = __builtin_amdgcn_mfma_f32_16x16x32_bf16(ahC[mf], bl, acc[mf][nt], 0, 0, 0);
      }
    }
    __syncthreads();
    if (more) {
      #pragma unroll
      for (int mf = 0; mf < 2; ++mf) { ahC[mf] = ahN[mf]; alC[mf] = alN[mf]; }
    }
  }

  #pragma unroll
  for (int mf = 0; mf < 2; ++mf) {
    const long rbase = blkrow + w * 32 + mf * 16 + g * 4;
    #pragma unroll
    for (int nt = 0; nt < 8; ++nt) {
      const int col = cb * 128 + nt * 16 + lr;
      const int u = col >> 6, o = col & 63;
      #pragma unroll
      for (int i = 0; i < 4; ++i)
        Wh[((long)u * N + (rbase + i)) * 64 + o] = acc[mf][nt][i];
    }
  }
}

// ---------------- recurrence over K=20 (gi precomputed, Whh in regs) -------------
__global__ __launch_bounds__(256, 2) void k_recur(
    const float* __restrict__ gi, const float* __restrict__ WhhT,
    const float* __restrict__ bhh, float* __restrict__ rout, const int seq0)
{
  const int tid = threadIdx.x, w = tid >> 6, l = tid & 63;
  const int lseq = blockIdx.x * 4 + w;
  float wr[64], wz[64], wn[64];
  #pragma unroll
  for (int k2 = 0; k2 < 64; ++k2) {
    wr[k2] = WhhT[k2 * 192 + l];
    wz[k2] = WhhT[k2 * 192 + 64 + l];
    wn[k2] = WhhT[k2 * 192 + 128 + l];
  }
  const float bR = bhh[l], bZ = bhh[64 + l], bN = bhh[128 + l];
  const float* __restrict__ grow = gi + (long)lseq * K * 192;
  float h = 0.f, rsum = 0.f;
  float gR = grow[l], gZ = grow[64 + l], gN = grow[128 + l];
  for (int k = 0; k < K; ++k) {
    float nR = 0.f, nZ = 0.f, nN = 0.f;
    if (k + 1 < K) {
      const int off = (k + 1) * 192;
      nR = grow[off + l]; nZ = grow[off + 64 + l]; nN = grow[off + 128 + l];
    }
    float aR = bR, aZ = bZ, aN = bN;
    #pragma unroll
    for (int k2 = 0; k2 < 64; ++k2) {
      const float hk = rdlane(h, k2);
      aR += wr[k2] * hk; aZ += wz[k2] * hk; aN += wn[k2] * hk;
    }
    const float r = sigm(gR + aR);
    const float z = sigm(gZ + aZ);
    const float nn = tanhf(gN + r * aN);
    h = (1.f - z) * nn + z * h;
    rsum += h;
    gR = nR; gZ = nZ; gN = nN;
  }
  const int gseq = seq0 + lseq;
  const int tt = gseq / N, n = gseq % N;
  rout[(n * T + tt) * H + l] = rsum;
}

// ---------------- p-GRU: inline gi (3-wide input), Whh in regs, T=5 --------------
__global__ __launch_bounds__(256, 2) void k_recur_p(
    const float* __restrict__ p, const float* __restrict__ Wih,
    const float* __restrict__ WhhT, const float* __restrict__ bih,
    const float* __restrict__ bhh, float* __restrict__ q)
{
  const int tid = threadIdx.x, w = tid >> 6, l = tid & 63;
  const int n = blockIdx.x * 4 + w;
  float wr[64], wz[64], wn[64];
  #pragma unroll
  for (int k2 = 0; k2 < 64; ++k2) {
    wr[k2] = WhhT[k2 * 192 + l];
    wz[k2] = WhhT[k2 * 192 + 64 + l];
    wn[k2] = WhhT[k2 * 192 + 128 + l];
  }
  float iR[3], iZ[3], iN[3];
  #pragma unroll
  for (int c = 0; c < 3; ++c) {
    iR[c] = Wih[l * 3 + c];
    iZ[c] = Wih[(64 + l) * 3 + c];
    iN[c] = Wih[(128 + l) * 3 + c];
  }
  const float biR = bih[l], biZ = bih[64 + l], biN = bih[128 + l];
  const float bhR = bhh[l], bhZ = bhh[64 + l], bhN = bhh[128 + l];
  float h = 0.f, qs = 0.f;
  for (int t = 0; t < T; ++t) {
    const float x0 = p[n * 15 + t * 3], x1 = p[n * 15 + t * 3 + 1], x2 = p[n * 15 + t * 3 + 2];
    const float gR = biR + iR[0] * x0 + iR[1] * x1 + iR[2] * x2;
    const float gZ = biZ + iZ[0] * x0 + iZ[1] * x1 + iZ[2] * x2;
    const float gN = biN + iN[0] * x0 + iN[1] * x1 + iN[2] * x2;
    float aR = bhR, aZ = bhZ, aN = bhN;
    #pragma unroll
    for (int k2 = 0; k2 < 64; ++k2) {
      const float hk = rdlane(h, k2);
      aR += wr[k2] * hk; aZ += wz[k2] * hk; aN += wn[k2] * hk;
    }
    const float r = sigm(gR + aR), z = sigm(gZ + aZ);
    const float nn = tanhf(gN + r * aN);
    h = (1.f - z) * nn + z * h;
    qs += h;
  }
  q[n * H + l] = qs;
}

// ---------------- s-GRU: gx precomputed (bias included), Whh in regs, T=5 --------
__global__ __launch_bounds__(256, 2) void k_recur_s(
    const float* __restrict__ gx, const float* __restrict__ WhhT,
    const float* __restrict__ bhh, float* __restrict__ c)
{
  const int tid = threadIdx.x, w = tid >> 6, l = tid & 63;
  const int n = blockIdx.x * 4 + w;
  float wr[64], wz[64], wn[64];
  #pragma unroll
  for (int k2 = 0; k2 < 64; ++k2) {
    wr[k2] = WhhT[k2 * 192 + l];
    wz[k2] = WhhT[k2 * 192 + 64 + l];
    wn[k2] = WhhT[k2 * 192 + 128 + l];
  }
  const float bR = bhh[l], bZ = bhh[64 + l], bN = bhh[128 + l];
  const float* __restrict__ grow = gx + (long)n * T * 192;
  float h = 0.f, cs = 0.f;
  for (int t = 0; t < T; ++t) {
    const float gR = grow[t * 192 + l], gZ = grow[t * 192 + 64 + l], gN = grow[t * 192 + 128 + l];
    float aR = bR, aZ = bZ, aN = bN;
    #pragma unroll
    for (int k2 = 0; k2 < 64; ++k2) {
      const float hk = rdlane(h, k2);
      aR += wr[k2] * hk; aZ += wz[k2] * hk; aN += wn[k2] * hk;
    }
    const float r = sigm(gR + aR), z = sigm(gZ + aZ);
    const float nn = tanhf(gN + r * aN);
    h = (1.f - z) * nn + z * h;
    cs += h;
  }
  c[n * H + l] = cs;
}

// ---------------- bilinear blend + relu (transposed W, 8 n per block) -----------
__global__ __launch_bounds__(256) void k_blend(
    const float* __restrict__ q, const float* __restrict__ c,
    const float* __restrict__ Wt2, const float* __restrict__ b,
    float* __restrict__ xout)
{
  __shared__ float qs[8][64];
  __shared__ alignas(16) float cs[8][64];
  const int tid = threadIdx.x;
  const int o = tid & 63, grp = tid >> 6;
  const int n0 = blockIdx.x * 8;
  for (int idx = tid; idx < 512; idx += 256) {
    qs[idx >> 6][idx & 63] = q[(n0 + (idx >> 6)) * 64 + (idx & 63)];
    cs[idx >> 6][idx & 63] = c[(n0 + (idx >> 6)) * 64 + (idx & 63)];
  }
  __syncthreads();
  const int na = grp * 2, nb = na + 1;
  float acca = b[o], accb = b[o];
  const float4* __restrict__ W4 = reinterpret_cast<const float4*>(Wt2);
  const float4* ca4 = reinterpret_cast<const float4*>(&cs[na][0]);
  const float4* cb4 = reinterpret_cast<const float4*>(&cs[nb][0]);
  for (int i = 0; i < 64; ++i) {
    float pa = 0.f, pb = 0.f;
    #pragma unroll
    for (int j4 = 0; j4 < 16; ++j4) {
      const float4 wv = W4[(i * 16 + j4) * 64 + o];
      const float4 va = ca4[j4], vb = cb4[j4];
      pa += wv.x * va.x + wv.y * va.y + wv.z * va.z + wv.w * va.w;
      pb += wv.x * vb.x + wv.y * vb.y + wv.z * vb.z + wv.w * vb.w;
    }
    acca += qs[na][i] * pa;
    accb += qs[nb][i] * pb;
  }
  xout[(n0 + na) * 64 + o] = fmaxf(acca, 0.f);
  xout[(n0 + nb) * 64 + o] = fmaxf(accb, 0.f);
}

// ---------------- adjacency compaction ----------------
__global__ __launch_bounds__(256) void k_compact(
    const float* __restrict__ adj, int* __restrict__ nbr, int* __restrict__ deg)
{
  const int w = threadIdx.x >> 6, lane = threadIdx.x & 63;
  const int i = blockIdx.x * 4 + w;
  int base = 0;
  for (int j0 = 0; j0 < N; j0 += 64) {
    const float v = adj[(long)i * N + j0 + lane];
    const unsigned long long mask = __ballot(v > 0.f);
    const int pre = __popcll(mask & ((1ull << lane) - 1ull));
    if (v > 0.f && base + pre < CAP) nbr[i * CAP + base + pre] = j0 + lane;
    base += __popcll(mask);
  }
  if (lane == 0) deg[i] = base < CAP ? base : CAP;
}

// ---------------- s1/s2 from precomputed Wh ----------------
__global__ __launch_bounds__(256) void k_s12(
    const float* __restrict__ Wh, const float* __restrict__ a,
    float* __restrict__ s1, float* __restrict__ s2)
{
  const int nl = threadIdx.x >> 6, o = threadIdx.x & 63;
  const int n = blockIdx.x * 4 + nl, u = blockIdx.y;
  const float acc = Wh[((long)u * N + n) * 64 + o];
  float p1 = acc * a[u * 128 + o];
  float p2 = acc * a[u * 128 + 64 + o];
  #pragma unroll
  for (int d = 32; d > 0; d >>= 1) { p1 += __shfl_xor(p1, d, 64); p2 += __shfl_xor(p2, d, 64); }
  if (o == 0) { s1[u * N + n] = p1; s2[u * N + n] = p2; }
}

// ---------------- GAT attention (two-phase, compacted) ----------------
__global__ __launch_bounds__(256) void k_gat_attn(
    const float* __restrict__ Wh, const float* __restrict__ s1,
    const float* __restrict__ s2, const int* __restrict__ nbr,
    const int* __restrict__ deg, const int mode, float* __restrict__ out)
{
  __shared__ float ew[4][CAP];
  __shared__ int nb[4][CAP];
  const int w = threadIdx.x >> 6, lane = threadIdx.x & 63;
  const int row = blockIdx.x * 4 + w;
  const int u = row >> 11;
  const int i = row & (N - 1);
  const int d = deg[i];
  const float su = s1[u * N + i];
  float mx = -1e30f;
  for (int t = lane; t < d; t += 64) {
    const int j = nbr[i * CAP + t];
    float e = su + s2[u * N + j];
    e = e > 0.f ? e : SLOPE * e;
    ew[w][t] = e; nb[w][t] = j;
    mx = fmaxf(mx, e);
  }
  #pragma unroll
  for (int dd = 32; dd > 0; dd >>= 1) mx = fmaxf(mx, __shfl_xor(mx, dd, 64));
  float sm = 0.f;
  for (int t = lane; t < d; t += 64) {
    const float ex = expf(ew[w][t] - mx);
    ew[w][t] = ex;
    sm += ex;
  }
  #pragma unroll
  for (int dd = 32; dd > 0; dd >>= 1) sm += __shfl_xor(sm, dd, 64);
  __syncthreads();
  const float inv = 1.f / sm;
  float acc = 0.f;
  for (int t = 0; t < d; ++t) {
    const float att = ew[w][t];
    const int j = nb[w][t];
    acc += att * Wh[((long)u * N + j) * 64 + lane];
  }
  acc *= inv;
  float val;
  if (mode == 0) val = acc > 0.f ? acc : (expf(acc) - 1.f);
  else           val = 1.f / (1.f + expf(-acc));
  out[(long)i * (U * 64) + u * 64 + lane] = val;
}

// ---------------- final projection + sigmoid ----------------
__global__ __launch_bounds__(256) void k_final(
    const float* __restrict__ nz, const float* __restrict__ fw,
    const float* __restrict__ fb, float* __restrict__ out)
{
  const int w = threadIdx.x >> 6, lane = threadIdx.x & 63;
  const int n = blockIdx.x * 4 + w;
  float p = 0.f;
  #pragma unroll
  for (int f = lane; f < 512; f += 64) p += nz[(long)n * 512 + f] * fw[f];
  #pragma unroll
  for (int d = 32; d > 0; d >>= 1) p += __shfl_xor(p, d, 64);
  if (lane == 0) out[n] = 1.f / (1.f + expf(-(p + fb[0])));
}

}  // namespace

extern "C" void kernel_launch(void* const* d_in, const int* in_sizes, int n_in,
                              void* d_out, int out_size, void* d_ws, size_t ws_size,
                              hipStream_t stream)
{
  const float* p     = (const float*)d_in[0];
  const float* m     = (const float*)d_in[1];
  const float* adj   = (const float*)d_in[2];
  const float* Wih_p = (const float*)d_in[3];
  const float* Whh_p = (const float*)d_in[4];
  const float* bih_p = (const float*)d_in[5];
  const float* bhh_p = (const float*)d_in[6];
  const float* Wih_m = (const float*)d_in[7];
  const float* Whh_m = (const float*)d_in[8];
  const float* bih_m = (const float*)d_in[9];
  const float* bhh_m = (const float*)d_in[10];
  const float* Wih_s = (const float*)d_in[11];
  const float* Whh_s = (const float*)d_in[12];
  const float* bih_s = (const float*)d_in[13];
  const float* bhh_s = (const float*)d_in[14];
  // d_in[15..23]: lin-attn weights — unused (softmax over size-1 axis == 1)
  const float* blend_W = (const float*)d_in[24];
  const float* blend_b = (const float*)d_in[25];
  const float* g1W = (const float*)d_in[26];
  const float* g1a = (const float*)d_in[27];
  const float* g2W = (const float*)d_in[28];
  const float* g2a = (const float*)d_in[29];
  const float* finW = (const float*)d_in[30];
  const float* finb = (const float*)d_in[31];

  float* ws = (float*)d_ws;
  float* q    = ws;                    // N*64
  float* rr   = q + N * H;             // N*T*64
  float* c    = rr + N * T * H;        // N*64
  float* xb   = c + N * H;             // N*64
  float* Wh1  = xb + N * H;            // U*N*64
  float* s1a  = Wh1 + U * N * 64;      // U*N
  float* s2a  = s1a + U * N;           // U*N
  float* z    = s2a + U * N;           // N*512
  float* Wh2  = z + (long)N * 512;     // U*N*64
  float* s1b  = Wh2 + U * N * 64;      // U*N
  float* s2b  = s1b + U * N;           // U*N
  float* nz   = s2b + U * N;           // N*512
  float* Wt2  = nz + (long)N * 512;    // 64*64*64
  float* gx   = Wt2 + 64 * 64 * 64;    // 10240*192
  float* WhhTm = gx + (long)10240 * 192;   // 64*192
  float* WhhTs = WhhTm + 64 * 192;
  float* WhhTp = WhhTs + 64 * 192;
  int*   nbr  = (int*)(WhhTp + 64 * 192);  // N*CAP
  int*   deg  = nbr + (long)N * CAP;       // N
  short* BfM  = (short*)(deg + N);         // 16*12288
  short* BfS  = BfM + 16 * 12288;          // 2*12288
  short* Bf1  = BfS + 2 * 12288;           // 4*2*8192
  short* Bf2  = Bf1 + 4 * 2 * 8192;        // 4*16*8192
  float* gi   = (float*)(Bf2 + 4 * 16 * 8192);   // chunked

  // chunk gi to whatever scratch remains (deterministic in ws_size)
  const long avail = (long)(ws_size / 4) - (gi - ws);
  const long total_seqs = (long)T * N;                 // 10240
  long chunk = (avail / ((long)K * 192) / 32) * 32;    // mult of 32 seqs (640 rows)
  if (chunk > total_seqs) chunk = total_seqs;
  if (chunk < 32) chunk = 32;

  k_prep<<<64, 256, 0, stream>>>(Wih_m, Whh_m, Wih_s, Whh_s, Whh_p, blend_W,
                                 BfM, BfS, WhhTm, WhhTs, WhhTp, Wt2);
  k_prep2<<<128, 256, 0, stream>>>(g2W, Bf2, 512);
  k_prep2<<<128, 256, 0, stream>>>(g1W, Bf1, 64);
  k_recur_p<<<N / 4, 256, 0, stream>>>(p, Wih_p, WhhTp, bih_p, bhh_p, q);
  for (long s0 = 0; s0 < total_seqs; s0 += chunk) {
    const long cs = (total_seqs - s0) < chunk ? (total_seqs - s0) : chunk;
    const long rows = cs * K;                          // multiple of 640
    k_gemm<<<(int)(rows / 128), 256, 0, stream>>>(m, BfM, bih_m, gi, s0 * K, 16, 512);
    k_recur<<<(int)(cs / 4), 256, 0, stream>>>(gi, WhhTm, bhh_m, rr, (int)s0);
  }
  k_gemm<<<80, 256, 0, stream>>>(rr, BfS, bih_s, gx, 0, 2, 64);
  k_recur_s<<<N / 4, 256, 0, stream>>>(gx, WhhTs, bhh_s, c);
  k_blend<<<N / 8, 256, 0, stream>>>(q, c, Wt2, blend_b, xb);
  k_compact<<<N / 4, 256, 0, stream>>>(adj, nbr, deg);
  k_gemmW<<<dim3(N / 128, 4), 256, 0, stream>>>(xb, Bf1, Wh1, 2, 64);
  k_s12<<<dim3(N / 4, U), 256, 0, stream>>>(Wh1, g1a, s1a, s2a);
  k_gat_attn<<<(U * N) / 4, 256, 0, stream>>>(Wh1, s1a, s2a, nbr, deg, 0, z);
  k_gemmW<<<dim3(N / 128, 4), 256, 0, stream>>>(z, Bf2, Wh2, 16, 512);
  k_s12<<<dim3(N / 4, U), 256, 0, stream>>>(Wh2, g2a, s1b, s2b);
  k_gat_attn<<<(U * N) / 4, 256, 0, stream>>>(Wh2, s1b, s2b, nbr, deg, 1, nz);
  k_final<<<N / 4, 256, 0, stream>>>(nz, finW, finb, (float*)d_out);
}